// Round 3
// baseline (1162.142 us; speedup 1.0000x reference)
//
#include <hip/hip_runtime.h>
#include <math.h>

#define TPB 256
constexpr int YC_STRIDE = 68096;  // 65536 + 10*256 region padding

// ---------------- workspace layout (bytes) ----------------
constexpr size_t OFF_COUNTS   = 0x000000; // 64 ints
constexpr size_t OFF_ACTIVE   = 0x000100; // 1 int
constexpr size_t OFF_LCNT     = 0x000140; // 10 ints
constexpr size_t OFF_RBASE    = 0x000180; // 10 ints
constexpr size_t OFF_MUSUM    = 0x000200; // 64 floats
constexpr size_t OFF_MU       = 0x000400; // 64 floats
constexpr size_t OFF_SSUM     = 0x000800; // float [4][9][256] partials
constexpr size_t OFF_SMEAN    = 0x00A000; // float [10][256]
constexpr size_t OFF_W1T      = 0x00D000; // [27][64]
constexpr size_t OFF_W3T      = 0x00F000; // [288][16]
constexpr size_t OFF_W2T      = 0x014000; // [576][32]
constexpr size_t OFF_CWT      = 0x028000; // [256][64]  compress_w^T
constexpr size_t OFF_POOLED   = 0x040000; // float [2][9][4096]
constexpr size_t OFF_M        = 0x090000; // float [2][9][4096]
constexpr size_t OFF_P        = 0x0E0000; // float [9][256][64]
constexpr size_t OFF_U        = 0x180000; // float [10][256][64]
constexpr size_t OFF_V        = 0x228000; // float [10][256]
constexpr size_t OFF_CBITS    = 0x230000; // int[65536]
constexpr size_t OFF_SBITS    = 0x270000; // int[65536]
constexpr size_t OFF_CBITS128 = 0x2B0000; // int[16384]
constexpr size_t OFF_SBITS128 = 0x2C0000; // int[16384]
constexpr size_t OFF_IDX      = 0x2D0000; // int [2][9][16384]
constexpr size_t OFF_BC       = 0x3F8000; // int [256][10]
constexpr size_t OFF_BBASE    = 0x400000; // int [256][10]
constexpr size_t OFF_RLIST    = 0x410000; // int [YC_STRIDE]
constexpr size_t OFF_INV      = 0x460000; // int [65536]
constexpr size_t OFF_XCT      = 0x700000; // float [65536][64]  Xc^T
constexpr size_t OFF_F1       = 0x1700000; // float [64][512][512]
constexpr size_t OFF_F2       = 0x5700000; // float [32][256][256]
constexpr size_t OFF_F3       = 0x5F00000; // float [16][128][128]
constexpr size_t OFF_YC       = OFF_F1;    // float [256][YC_STRIDE] (reuses dead F1+F2)

__global__ void init_k(int* p, int n) {
    for (int i = blockIdx.x * TPB + threadIdx.x; i < n; i += gridDim.x * TPB) p[i] = 0;
}

// ---------------- mask bit planes + counts ----------------
__global__ void bits_k(const int* __restrict__ cm, const int* __restrict__ sm,
                       int* __restrict__ cbits, int* __restrict__ sbits, int* __restrict__ counts) {
    int p = blockIdx.x * TPB + threadIdx.x;
    int cb = 0, sb = 0;
#pragma unroll
    for (int r = 0; r < 9; ++r) {
        cb |= (cm[r * 65536 + p] == 1) << r;
        sb |= (sm[r * 65536 + p] == 1) << r;
    }
    cbits[p] = cb; sbits[p] = sb;
    int lane = threadIdx.x & 63;
#pragma unroll
    for (int r = 0; r < 9; ++r) {
        unsigned long long b1 = __ballot((cb >> r) & 1);
        if (lane == 0) atomicAdd(&counts[0 + r], __popcll(b1));
        unsigned long long b2 = __ballot((sb >> r) & 1);
        if (lane == 0) atomicAdd(&counts[16 + r], __popcll(b2));
    }
}

__global__ void bits128_k(const int* __restrict__ cm, const int* __restrict__ sm,
                          int* __restrict__ cbits128, int* __restrict__ sbits128, int* __restrict__ counts) {
    int p = blockIdx.x * TPB + threadIdx.x;
    int y = p >> 7, x = p & 127;
    int src = (2 * y) * 256 + 2 * x;
    int cb = 0, sb = 0;
#pragma unroll
    for (int r = 0; r < 9; ++r) {
        cb |= (cm[r * 65536 + src] == 1) << r;
        sb |= (sm[r * 65536 + src] == 1) << r;
    }
    cbits128[p] = cb; sbits128[p] = sb;
    int lane = threadIdx.x & 63;
#pragma unroll
    for (int r = 0; r < 9; ++r) {
        unsigned long long b1 = __ballot((cb >> r) & 1);
        if (lane == 0) atomicAdd(&counts[32 + r], __popcll(b1));
        unsigned long long b2 = __ballot((sb >> r) & 1);
        if (lane == 0) atomicAdd(&counts[48 + r], __popcll(b2));
    }
}

// ---------------- ordered compaction at 128x128 (ballot scan, 2 barriers/chunk) -----
__global__ void compact_k(const int* __restrict__ sbits128, const int* __restrict__ cbits128,
                          int* __restrict__ idxlist) {
    int r = blockIdx.x, side = blockIdx.y;
    const int* bits = side ? cbits128 : sbits128;
    int* outp = idxlist + (side * 9 + r) * 16384;
    __shared__ int wcnt[4];
    __shared__ int base_s;
    int t = threadIdx.x, w = t >> 6, lane = t & 63;
    if (t == 0) base_s = 0;
    __syncthreads();
    for (int chunk = 0; chunk < 64; ++chunk) {
        int pid = chunk * 256 + t;
        int flag = (bits[pid] >> r) & 1;
        unsigned long long m = __ballot(flag);
        if (lane == 0) wcnt[w] = __popcll(m);
        __syncthreads();
        int base = base_s;
        int woff = 0;
        for (int w2 = 0; w2 < w; ++w2) woff += wcnt[w2];
        if (flag) outp[base + woff + __popcll(m & ((1ull << lane) - 1ull))] = pid;
        __syncthreads();
        if (t == 0) base_s = base + wcnt[0] + wcnt[1] + wcnt[2] + wcnt[3];
    }
}

// ---------------- weight transpose [oc][ick] -> [ick][oc] ----------------
__global__ void wtr_k(const float* __restrict__ w, float* __restrict__ wT, int OC, int ICK) {
    int i = blockIdx.x * TPB + threadIdx.x;
    int n = OC * ICK;
    if (i < n) {
        int oc = i / ICK;
        int t = i - oc * ICK;
        wT[t * OC + oc] = w[i];
    }
}

// ---------------- per-region style mean partial sums ----------------
__global__ void smean_k(const float* __restrict__ sF, const int* __restrict__ sbits,
                        float* __restrict__ ssump) {
    int c = blockIdx.x;
    int pg = blockIdx.y;
    int t = threadIdx.x;
    float acc[9];
#pragma unroll
    for (int r = 0; r < 9; ++r) acc[r] = 0.f;
    int p0 = pg * 16384;
    for (int p = p0 + t; p < p0 + 16384; p += TPB) {
        float v = sF[c * 65536 + p];
        int b = sbits[p];
#pragma unroll
        for (int r = 0; r < 9; ++r)
            if (b & (1 << r)) acc[r] += v;
    }
    __shared__ float red[9 * TPB];
#pragma unroll
    for (int r = 0; r < 9; ++r) red[r * TPB + t] = acc[r];
    __syncthreads();
    for (int off = TPB / 2; off > 0; off >>= 1) {
        if (t < off)
#pragma unroll
            for (int r = 0; r < 9; ++r) red[r * TPB + t] += red[r * TPB + t + off];
        __syncthreads();
    }
    if (t < 9) ssump[(pg * 9 + t) * 256 + c] = red[t * TPB];
}

// ---------------- active mask + per-region style means ----------------
__global__ void finalize_k(const int* __restrict__ counts, int* __restrict__ activemask,
                           const float* __restrict__ ssump, float* __restrict__ sMeanArr) {
    __shared__ int am;
    if (threadIdx.x == 0) am = 0;
    __syncthreads();
    if (threadIdx.x < 9) {
        int r = threadIdx.x;
        if (counts[0 + r] >= 10 && counts[16 + r] >= 10 && counts[32 + r] >= 10 && counts[48 + r] >= 10)
            atomicOr(&am, 1 << r);
    }
    __syncthreads();
    if (threadIdx.x == 0) *activemask = am;
    for (int e = threadIdx.x; e < 2560; e += TPB) {
        int r = e >> 8, c = e & 255;
        float v = 0.f;
        if (r < 9 && ((am >> r) & 1)) {
            float s = ssump[(0 * 9 + r) * 256 + c] + ssump[(1 * 9 + r) * 256 + c]
                    + ssump[(2 * 9 + r) * 256 + c] + ssump[(3 * 9 + r) * 256 + c];
            v = s / (float)counts[16 + r];
        }
        sMeanArr[e] = v;
    }
}

// ---------------- stable region ranking at 256-res: hist -> scan -> rank -------------
__global__ void hist_k(const int* __restrict__ cbits, const int* __restrict__ activemask,
                       int* __restrict__ rmap, int* __restrict__ bc) {
    int b = blockIdx.x, t = threadIdx.x;
    int p = b * 256 + t;
    int am = *activemask;
    int bits = cbits[p] & am;
    int r = bits ? (31 - __clz(bits)) : 9;
    rmap[p] = r;
    __shared__ int wc[4][10];
    int w = t >> 6, lane = t & 63;
#pragma unroll
    for (int rr = 0; rr < 10; ++rr) {
        unsigned long long m = __ballot(r == rr);
        if (lane == rr) wc[w][rr] = __popcll(m);
    }
    __syncthreads();
    if (t < 10) bc[b * 10 + t] = wc[0][t] + wc[1][t] + wc[2][t] + wc[3][t];
}

__global__ void scan_k(const int* __restrict__ bc, int* __restrict__ bbase,
                       int* __restrict__ lcnt, int* __restrict__ rbase) {
    __shared__ int tot[10], Bs[16];
    int t = threadIdx.x;
    if (t < 10) {
        int s = 0;
        for (int b = 0; b < 256; ++b) s += bc[b * 10 + t];
        tot[t] = s;
    }
    __syncthreads();
    if (t == 0) {
        int run = 0;
        for (int r = 0; r < 10; ++r) { Bs[r] = run; run += (tot[r] + 255) & ~255; }
    }
    __syncthreads();
    if (t < 10) {
        lcnt[t] = tot[t];
        rbase[t] = Bs[t];
        int run = Bs[t];
        for (int b = 0; b < 256; ++b) { bbase[b * 10 + t] = run; run += bc[b * 10 + t]; }
    }
}

__global__ void rank_k(const int* __restrict__ rmap, const int* __restrict__ bbase,
                       int* __restrict__ inv, int* __restrict__ rlist) {
    int b = blockIdx.x, t = threadIdx.x;
    int p = b * 256 + t;
    int r = rmap[p];
    __shared__ int wc[4][10];
    int w = t >> 6, lane = t & 63;
    int prefix = 0;
#pragma unroll
    for (int rr = 0; rr < 10; ++rr) {
        unsigned long long m = __ballot(r == rr);
        if (rr == r) prefix = __popcll(m & ((1ull << lane) - 1ull));
        if (lane == rr) wc[w][rr] = __popcll(m);
    }
    __syncthreads();
    int woff = 0;
    for (int w2 = 0; w2 < w; ++w2) woff += wc[w2][r];
    int g = bbase[b * 10 + r] + woff + prefix;
    inv[p] = g;
    rlist[g] = p;
}

// ---------------- helpers for 4px x 8oc conv tiling ----------------
__device__ __forceinline__ void ld8(float* d, const float* __restrict__ p) {
    float4 a = *(const float4*)p;
    float4 b = *(const float4*)(p + 4);
    d[0] = a.x; d[1] = a.y; d[2] = a.z; d[3] = a.w;
    d[4] = b.x; d[5] = b.y; d[6] = b.z; d[7] = b.w;
}

// ---------------- conv1: 1024x1024x3 -> 512x512x64, LDS ev/od, 4px x 8oc ----------
// block = half an output row (256 px); og32-split 2. Thread t: px group g=t&63
// (pixels 4g..4g+3), oc group og=t>>6 (8 ocs). Weight loads wave-uniform.
__global__ void conv1_k(const float* __restrict__ in, const float* __restrict__ wT,
                        const float* __restrict__ b, float* __restrict__ out) {
    int oy = blockIdx.x >> 1;
    int X0 = (blockIdx.x & 1) << 8;    // 0 or 256
    int og32 = blockIdx.y;
    int t = threadIdx.x;
    int g = t & 63;
    int og = __builtin_amdgcn_readfirstlane(t >> 6);   // wave-uniform 8-oc group
    __shared__ float ev[3][3][260];
    __shared__ float od[3][3][264];
    // stage interior: 3 ic x 3 rows x 128 float4 (coalesced), de-interleaved into ev/od
    for (int u = t; u < 1152; u += 256) {
        int ic = u / 384;
        int rem = u - ic * 384;
        int row = rem >> 7, q = rem & 127;
        int iy = 2 * oy - 1 + row;
        float4 v = make_float4(0.f, 0.f, 0.f, 0.f);
        if ((unsigned)iy < 1024u)
            v = *(const float4*)(in + ic * 1048576 + iy * 1024 + 2 * X0 + 4 * q);
        ev[ic][row][2 * q]     = v.x;   // x=4q
        od[ic][row][2 * q + 1] = v.y;   // x=4q+1
        ev[ic][row][2 * q + 1] = v.z;   // x=4q+2
        od[ic][row][2 * q + 2] = v.w;   // x=4q+3
    }
    // left halo (x = -1, i.e. ix = 2*X0 - 1)
    if (t < 9) {
        int ic = t / 3, row = t % 3;
        int iy = 2 * oy - 1 + row;
        int ix = 2 * X0 - 1;
        float v = 0.f;
        if ((unsigned)iy < 1024u && ix >= 0) v = in[ic * 1048576 + iy * 1024 + ix];
        od[ic][row][0] = v;
    }
    __syncthreads();
    int ocb = og32 * 32 + og * 8;
    float bias[8];
    ld8(bias, b + ocb);
    float acc[4][8];
#pragma unroll
    for (int j = 0; j < 4; ++j)
#pragma unroll
        for (int c = 0; c < 8; ++c) acc[j][c] = bias[c];
#pragma unroll
    for (int ic = 0; ic < 3; ++ic)
#pragma unroll
        for (int ky = 0; ky < 3; ++ky) {
            float4 e4 = *(const float4*)&ev[ic][ky][4 * g];
            float4 o4 = *(const float4*)&od[ic][ky][4 * g];
            float  o5 = od[ic][ky][4 * g + 4];
            float e_[4] = {e4.x, e4.y, e4.z, e4.w};
            float o_[5] = {o4.x, o4.y, o4.z, o4.w, o5};
            const float* wbase = wT + (ic * 9 + ky * 3) * 64 + ocb;
            float wA[8], wB[8], wC[8];
            ld8(wA, wbase);            // kx = 0
            ld8(wB, wbase + 64);       // kx = 1
            ld8(wC, wbase + 128);      // kx = 2
#pragma unroll
            for (int j = 0; j < 4; ++j) {
                float v0 = o_[j], v1 = e_[j], v2 = o_[j + 1];
#pragma unroll
                for (int c = 0; c < 8; ++c)
                    acc[j][c] = fmaf(wA[c], v0, fmaf(wB[c], v1, fmaf(wC[c], v2, acc[j][c])));
            }
        }
    int idx = oy * 512 + X0 + 4 * g;
#pragma unroll
    for (int c = 0; c < 8; ++c) {
        float4 o = make_float4(fmaxf(acc[0][c], 0.f), fmaxf(acc[1][c], 0.f),
                               fmaxf(acc[2][c], 0.f), fmaxf(acc[3][c], 0.f));
        *(float4*)(out + (size_t)(ocb + c) * 262144 + idx) = o;
    }
}

// ---------------- conv2: bias init, ic-split-4 atomic partials, relu ----------------
__global__ void f2init_k(const float* __restrict__ b, float* __restrict__ F2) {
    int idx = blockIdx.x * TPB + threadIdx.x;
#pragma unroll
    for (int oc = 0; oc < 32; ++oc) F2[oc * 65536 + idx] = b[oc];
}

// conv2: block = one output row (256 px), 4px x 8oc per thread, double-buffered
// ev/od LDS tile, async-STAGE split (issue loads -> compute -> ds_write -> barrier).
__device__ __forceinline__ void c2_load(const float* __restrict__ base, int oy, int t,
                                        float4& r0, float4& r1) {
    int row0 = t >> 7, q0 = t & 127;     // rows 0,1
    int iy0 = 2 * oy - 1 + row0;
    r0 = make_float4(0.f, 0.f, 0.f, 0.f);
    if ((unsigned)iy0 < 512u) r0 = *(const float4*)(base + iy0 * 512 + 4 * q0);
    r1 = make_float4(0.f, 0.f, 0.f, 0.f);
    if (t < 128) {                        // row 2: iy = 2*oy+1, always in range
        int iy1 = 2 * oy + 1;
        r1 = *(const float4*)(base + iy1 * 512 + 4 * t);
    }
}

__device__ __forceinline__ void c2_store(float (*ev)[260], float (*od)[264], int t,
                                         float4 r0, float4 r1) {
    int row0 = t >> 7, q0 = t & 127;
    ev[row0][2 * q0]     = r0.x;   // x=4q
    od[row0][2 * q0 + 1] = r0.y;   // x=4q+1
    ev[row0][2 * q0 + 1] = r0.z;   // x=4q+2
    od[row0][2 * q0 + 2] = r0.w;   // x=4q+3
    if (t < 128) {
        ev[2][2 * t]     = r1.x;
        od[2][2 * t + 1] = r1.y;
        ev[2][2 * t + 1] = r1.z;
        od[2][2 * t + 2] = r1.w;
    }
}

__device__ __forceinline__ void c2_compute(const float* __restrict__ wT, int ic,
                                           const float (*ev)[260], const float (*od)[264],
                                           int g, int og, float (*acc)[8]) {
#pragma unroll
    for (int ky = 0; ky < 3; ++ky) {
        float4 e4 = *(const float4*)&ev[ky][4 * g];
        float4 o4 = *(const float4*)&od[ky][4 * g];
        float  o5 = od[ky][4 * g + 4];
        float e_[4] = {e4.x, e4.y, e4.z, e4.w};
        float o_[5] = {o4.x, o4.y, o4.z, o4.w, o5};
        const float* wbase = wT + (ic * 9 + ky * 3) * 32 + og * 8;
        float wA[8], wB[8], wC[8];
        ld8(wA, wbase);           // kx = 0
        ld8(wB, wbase + 32);      // kx = 1
        ld8(wC, wbase + 64);      // kx = 2
#pragma unroll
        for (int j = 0; j < 4; ++j) {
            float v0 = o_[j], v1 = e_[j], v2 = o_[j + 1];
#pragma unroll
            for (int c = 0; c < 8; ++c)
                acc[j][c] = fmaf(wA[c], v0, fmaf(wB[c], v1, fmaf(wC[c], v2, acc[j][c])));
        }
    }
}

__global__ void conv2p_k(const float* __restrict__ in, const float* __restrict__ wT,
                         float* __restrict__ F2) {
    int oy = blockIdx.x;      // 0..255
    int icg = blockIdx.y;     // 0..3
    int t = threadIdx.x;
    int g = t & 63;
    int og = __builtin_amdgcn_readfirstlane(t >> 6);   // wave-uniform 8-oc group
    __shared__ float ev[2][3][260];
    __shared__ float od[2][3][264];
    if (t < 6) od[t / 3][t % 3][0] = 0.f;   // left halo (x = -1) stays zero, both buffers
    float acc[4][8];
#pragma unroll
    for (int j = 0; j < 4; ++j)
#pragma unroll
        for (int c = 0; c < 8; ++c) acc[j][c] = 0.f;
    int ic0 = icg * 16;
    float4 r0, r1;
    c2_load(in + ic0 * 262144, oy, t, r0, r1);
    c2_store(ev[0], od[0], t, r0, r1);
    __syncthreads();
#pragma unroll 1
    for (int i = 0; i < 16; i += 2) {
        c2_load(in + (ic0 + i + 1) * 262144, oy, t, r0, r1);   // issue loads early
        c2_compute(wT, ic0 + i, ev[0], od[0], g, og, acc);     // hide latency under FMAs
        c2_store(ev[1], od[1], t, r0, r1);                     // vmcnt drained after compute
        __syncthreads();
        if (i + 2 < 16) c2_load(in + (ic0 + i + 2) * 262144, oy, t, r0, r1);
        c2_compute(wT, ic0 + i + 1, ev[1], od[1], g, og, acc);
        if (i + 2 < 16) c2_store(ev[0], od[0], t, r0, r1);
        __syncthreads();
    }
    int base = oy * 256 + 4 * g;
#pragma unroll
    for (int c = 0; c < 8; ++c)
#pragma unroll
        for (int j = 0; j < 4; ++j)
            atomicAdd(&F2[(og * 8 + c) * 65536 + base + j], acc[j][c]);
}

__global__ void relu2_k(float* __restrict__ F2) {
    int i = blockIdx.x * TPB + threadIdx.x;
    float4* p = (float4*)F2;
    float4 v = p[i];
    v.x = fmaxf(v.x, 0.f); v.y = fmaxf(v.y, 0.f);
    v.z = fmaxf(v.z, 0.f); v.w = fmaxf(v.w, 0.f);
    p[i] = v;
}

// ---------------- conv3: bias init + ic-split-4 atomic partials (no relu) ------------
__global__ void f3init_k(const float* __restrict__ b, float* __restrict__ F3) {
    int idx = blockIdx.x * TPB + threadIdx.x;
#pragma unroll
    for (int oc = 0; oc < 16; ++oc) F3[oc * 16384 + idx] = b[oc];
}

__global__ void conv3p_k(const float* __restrict__ in, const float* __restrict__ wT,
                         float* __restrict__ F3) {
    int idx = blockIdx.x * TPB + threadIdx.x;
    int icg = blockIdx.y;
    int ox = idx & 127, oy = idx >> 7;
    float acc[16];
#pragma unroll
    for (int oc = 0; oc < 16; ++oc) acc[oc] = 0.f;
    for (int ic = icg * 8; ic < icg * 8 + 8; ++ic) {
        const float* base = in + ic * 65536;
#pragma unroll
        for (int ky = 0; ky < 3; ++ky) {
            int iy = 2 * oy - 1 + ky;
            if ((unsigned)iy < 256u)
#pragma unroll
                for (int kx = 0; kx < 3; ++kx) {
                    int ix = 2 * ox - 1 + kx;
                    if ((unsigned)ix < 256u) {
                        float v = base[iy * 256 + ix];
                        const float4* wp = (const float4*)(wT + (ic * 9 + ky * 3 + kx) * 16);
#pragma unroll
                        for (int q = 0; q < 4; ++q) {
                            float4 w4 = wp[q];
                            acc[q * 4 + 0] = fmaf(w4.x, v, acc[q * 4 + 0]);
                            acc[q * 4 + 1] = fmaf(w4.y, v, acc[q * 4 + 1]);
                            acc[q * 4 + 2] = fmaf(w4.z, v, acc[q * 4 + 2]);
                            acc[q * 4 + 3] = fmaf(w4.w, v, acc[q * 4 + 3]);
                        }
                    }
                }
        }
    }
#pragma unroll
    for (int oc = 0; oc < 16; ++oc) atomicAdd(&F3[oc * 16384 + idx], acc[oc]);
}

// ---------------- adaptive max pool over ordered compacted indices ----------------
__global__ void pool_k(const float* __restrict__ f3, const int* __restrict__ idxbase,
                       const int* __restrict__ cnt, float* __restrict__ pooled) {
    int r = blockIdx.x >> 4;
    int c = blockIdx.x & 15;
    int j = threadIdx.x;
    int n = cnt[r];
    float m = 0.f;
    if (n >= 1) {
        int start = (j * n) >> 8;
        int end = ((j + 1) * n + 255) >> 8;
        const int* il = idxbase + r * 16384;
        m = -__builtin_inff();
        for (int t = start; t < end; ++t) m = fmaxf(m, f3[c * 16384 + il[t]]);
    }
    pooled[(r * 16 + c) * 256 + j] = m;
}

// ---------------- FC: M[side][r][row] (9 cols batched per row-block) ----------------
__global__ void fc_k(const float* __restrict__ fcw_s, const float* __restrict__ fcb_s,
                     const float* __restrict__ fcw_c, const float* __restrict__ fcb_c,
                     const float* __restrict__ pooled, float* __restrict__ Mout) {
    int row = blockIdx.x;
    int side = blockIdx.y;
    const float* fcw = side ? fcw_c : fcw_s;
    const float* fcb = side ? fcb_c : fcb_s;
    const float* P = pooled + side * 9 * 4096;
    int t = threadIdx.x;
    float acc[9];
#pragma unroll
    for (int r = 0; r < 9; ++r) acc[r] = 0.f;
    for (int k = t; k < 4096; k += TPB) {
        float w = fcw[row * 4096 + k];
#pragma unroll
        for (int r = 0; r < 9; ++r) acc[r] = fmaf(w, P[r * 4096 + k], acc[r]);
    }
    __shared__ float red[9 * TPB];
#pragma unroll
    for (int r = 0; r < 9; ++r) red[r * TPB + t] = acc[r];
    __syncthreads();
    for (int off = TPB / 2; off > 0; off >>= 1) {
        if (t < off)
#pragma unroll
            for (int r = 0; r < 9; ++r) red[r * TPB + t] += red[r * TPB + t + off];
        __syncthreads();
    }
    if (t < 9) Mout[(side * 9 + t) * 4096 + row] = red[t * TPB] + fcb[row];
}

// ---------------- Xc^T = (compress_w @ cF)^T, m-split 4 ----------------
__global__ void xgemm_k(const float* __restrict__ cF, const float* __restrict__ cwT,
                        float* __restrict__ XcT) {
    int p = blockIdx.x * TPB + threadIdx.x;
    int m0 = blockIdx.y * 16;
    float acc[16];
#pragma unroll
    for (int m = 0; m < 16; ++m) acc[m] = 0.f;
    for (int k0 = 0; k0 < 256; k0 += 4) {
        float xv[4];
#pragma unroll
        for (int i = 0; i < 4; ++i) xv[i] = cF[(k0 + i) * 65536 + p];
#pragma unroll
        for (int i = 0; i < 4; ++i) {
            const float4* wp = (const float4*)(cwT + (k0 + i) * 64 + m0);
#pragma unroll
            for (int q = 0; q < 4; ++q) {
                float4 w4 = wp[q];
                acc[q * 4 + 0] = fmaf(w4.x, xv[i], acc[q * 4 + 0]);
                acc[q * 4 + 1] = fmaf(w4.y, xv[i], acc[q * 4 + 1]);
                acc[q * 4 + 2] = fmaf(w4.z, xv[i], acc[q * 4 + 2]);
                acc[q * 4 + 3] = fmaf(w4.w, xv[i], acc[q * 4 + 3]);
            }
        }
    }
    float4* op = (float4*)(XcT + p * 64 + m0);
#pragma unroll
    for (int q = 0; q < 4; ++q)
        op[q] = make_float4(acc[q * 4 + 0], acc[q * 4 + 1], acc[q * 4 + 2], acc[q * 4 + 3]);
}

// ---------------- mu from Xc^T ----------------
__global__ void muacc_k(const float* __restrict__ XcT, float* __restrict__ musum) {
    int t = threadIdx.x;
    int m = t & 63, sub = t >> 6;
    int p0 = blockIdx.x * 256;
    float a = 0.f;
    for (int i = 0; i < 64; ++i) a += XcT[(p0 + sub + i * 4) * 64 + m];
    __shared__ float red[TPB];
    red[t] = a;
    __syncthreads();
    if (t < 64) atomicAdd(&musum[t], red[t] + red[t + 64] + red[t + 128] + red[t + 192]);
}

__global__ void mufin_k(const float* __restrict__ musum, float* __restrict__ mu) {
    int t = threadIdx.x;
    if (t < 64) mu[t] = musum[t] * (1.f / 65536.f);
}

// ---------------- U/V precompute ----------------
__global__ void uprep1_k(const float* __restrict__ uw, const float* __restrict__ M,
                         float* __restrict__ P) {
    int idx = blockIdx.x * TPB + threadIdx.x;
    int r = idx / 16384;
    int rem = idx & 16383;
    int c = rem >> 6, k = rem & 63;
    float a = 0.f;
#pragma unroll 8
    for (int i = 0; i < 64; ++i) a = fmaf(uw[c * 64 + i], M[r * 4096 + i * 64 + k], a);
    P[idx] = a;
}

__global__ void uprep2_k(const float* __restrict__ uw, const float* __restrict__ M,
                         const float* __restrict__ P, float* __restrict__ U) {
    int idx = blockIdx.x * TPB + threadIdx.x;
    int r = idx / 16384;
    int rem = idx & 16383;
    int c = rem >> 6, j = rem & 63;
    if (r == 9) { U[idx] = uw[c * 64 + j]; return; }
    float a = 0.f;
#pragma unroll 8
    for (int k = 0; k < 64; ++k) a = fmaf(P[r * 16384 + c * 64 + k], M[(9 + r) * 4096 + k * 64 + j], a);
    U[idx] = a;
}

__global__ void uprep3_k(const float* __restrict__ U, const float* __restrict__ mu,
                         const float* __restrict__ uzb, const float* __restrict__ sMeanArr,
                         float* __restrict__ V) {
    int r = blockIdx.x;
    int c = threadIdx.x;
    float a = uzb[c] + sMeanArr[r * 256 + c];
#pragma unroll 8
    for (int j = 0; j < 64; ++j) a -= U[r * 16384 + c * 64 + j] * mu[j];
    V[r * 256 + c] = a;
}

// ---------------- Yc[oc][rank] = U_r @ Xc + V_r  (coalesced full-line writes) --------
__global__ void ygemm_k(const float* __restrict__ XcT, const float* __restrict__ U,
                        const float* __restrict__ V, const int* __restrict__ lcnt,
                        const int* __restrict__ rbase, const int* __restrict__ rlist,
                        float* __restrict__ Yc) {
    int r = blockIdx.x >> 8;
    int c = blockIdx.x & 255;
    int ocg = blockIdx.y;
    int n = lcnt[r];
    int start = c * 256;
    if (start >= n) return;
    int i = start + threadIdx.x;
    bool valid = i < n;
    int gi = rbase[r] + (valid ? i : n - 1);
    int pix = rlist[gi];
    float4 xv[16];
    const float4* xp = (const float4*)(XcT + (size_t)pix * 64);
#pragma unroll
    for (int q = 0; q < 16; ++q) xv[q] = xp[q];
    const float* Ur = U + r * 16384 + ocg * 4096;
    const float* Vr = V + r * 256 + ocg * 64;
#pragma unroll 4
    for (int oc = 0; oc < 64; ++oc) {
        float a = Vr[oc];
        const float4* up = (const float4*)(Ur + oc * 64);
#pragma unroll
        for (int q = 0; q < 16; ++q) {
            float4 u4 = up[q];
            a = fmaf(u4.x, xv[q].x, a);
            a = fmaf(u4.y, xv[q].y, a);
            a = fmaf(u4.z, xv[q].z, a);
            a = fmaf(u4.w, xv[q].w, a);
        }
        if (valid) Yc[(size_t)(ocg * 64 + oc) * YC_STRIDE + gi] = a;   // store now: no acc[], no spill
    }
}

// ---------------- merge: out[oc][p] = Yc[oc][inv[p]]  (coalesced output writes) ------
__global__ void merge_k(const float* __restrict__ Yc, const int* __restrict__ inv,
                        float* __restrict__ out) {
    int p = blockIdx.x * TPB + threadIdx.x;
    int oc0 = blockIdx.y * 4;
    int gi = inv[p];
#pragma unroll
    for (int j = 0; j < 4; ++j)
        out[(size_t)(oc0 + j) * 65536 + p] = Yc[(size_t)(oc0 + j) * YC_STRIDE + gi];
}

// ---------------- launch ----------------
extern "C" void kernel_launch(void* const* d_in, const int* in_sizes, int n_in,
                              void* d_out, int out_size, void* d_ws, size_t ws_size,
                              hipStream_t stream) {
    const float* cF         = (const float*)d_in[0];
    const float* sF         = (const float*)d_in[1];
    const float* content    = (const float*)d_in[2];
    const float* style      = (const float*)d_in[3];
    const int*   cmasks     = (const int*)d_in[4];
    const int*   smasks     = (const int*)d_in[5];
    const float* compress_w = (const float*)d_in[6];
    const float* unzip_w    = (const float*)d_in[8];
    const float* unzip_b    = (const float*)d_in[9];
    const float* s_w1 = (const float*)d_in[10]; const float* s_b1 = (const float*)d_in[11];
    const float* s_w2 = (const float*)d_in[12]; const float* s_b2 = (const float*)d_in[13];
    const float* s_w3 = (const float*)d_in[14]; const float* s_b3 = (const float*)d_in[15];
    const float* s_fcw = (const float*)d_in[16]; const float* s_fcb = (const float*)d_in[17];
    const float* c_w1 = (const float*)d_in[18]; const float* c_b1 = (const float*)d_in[19];
    const float* c_w2 = (const float*)d_in[20]; const float* c_b2 = (const float*)d_in[21];
    const float* c_w3 = (const float*)d_in[22]; const float* c_b3 = (const float*)d_in[23];
    const float* c_fcw = (const float*)d_in[24]; const float* c_fcb = (const float*)d_in[25];
    float* out = (float*)d_out;
    char* ws = (char*)d_ws;
#define WF(o) ((float*)(ws + (o)))
#define WI(o) ((int*)(ws + (o)))

    init_k<<<1, TPB, 0, stream>>>(WI(0), 256);   // counts, active, musum
    bits_k<<<256, TPB, 0, stream>>>(cmasks, smasks, WI(OFF_CBITS), WI(OFF_SBITS), WI(OFF_COUNTS));
    bits128_k<<<64, TPB, 0, stream>>>(cmasks, smasks, WI(OFF_CBITS128), WI(OFF_SBITS128), WI(OFF_COUNTS));
    compact_k<<<dim3(9, 2), TPB, 0, stream>>>(WI(OFF_SBITS128), WI(OFF_CBITS128), WI(OFF_IDX));
    smean_k<<<dim3(256, 4), TPB, 0, stream>>>(sF, WI(OFF_SBITS), WF(OFF_SSUM));
    finalize_k<<<1, TPB, 0, stream>>>(WI(OFF_COUNTS), WI(OFF_ACTIVE), WF(OFF_SSUM), WF(OFF_SMEAN));

    // stable region ranking
    hist_k<<<256, TPB, 0, stream>>>(WI(OFF_CBITS), WI(OFF_ACTIVE), WI(OFF_INV) /*tmp rmap*/, WI(OFF_BC));
    scan_k<<<1, TPB, 0, stream>>>(WI(OFF_BC), WI(OFF_BBASE), WI(OFF_LCNT), WI(OFF_RBASE));
    rank_k<<<256, TPB, 0, stream>>>(WI(OFF_INV) /*rmap in*/, WI(OFF_BBASE), WI(OFF_INV), WI(OFF_RLIST));

    // Xc^T (compress)
    wtr_k<<<64, TPB, 0, stream>>>(compress_w, WF(OFF_CWT), 64, 256);
    xgemm_k<<<dim3(256, 4), TPB, 0, stream>>>(cF, WF(OFF_CWT), WF(OFF_XCT));
    muacc_k<<<256, TPB, 0, stream>>>(WF(OFF_XCT), WF(OFF_MUSUM));
    mufin_k<<<1, 64, 0, stream>>>(WF(OFF_MUSUM), WF(OFF_MU));

    // style CNN
    wtr_k<<<7, TPB, 0, stream>>>(s_w1, WF(OFF_W1T), 64, 27);
    wtr_k<<<72, TPB, 0, stream>>>(s_w2, WF(OFF_W2T), 32, 576);
    wtr_k<<<18, TPB, 0, stream>>>(s_w3, WF(OFF_W3T), 16, 288);
    conv1_k<<<dim3(1024, 2), TPB, 0, stream>>>(style, WF(OFF_W1T), s_b1, WF(OFF_F1));
    f2init_k<<<256, TPB, 0, stream>>>(s_b2, WF(OFF_F2));
    conv2p_k<<<dim3(256, 4), TPB, 0, stream>>>(WF(OFF_F1), WF(OFF_W2T), WF(OFF_F2));
    relu2_k<<<2048, TPB, 0, stream>>>(WF(OFF_F2));
    f3init_k<<<64, TPB, 0, stream>>>(s_b3, WF(OFF_F3));
    conv3p_k<<<dim3(64, 4), TPB, 0, stream>>>(WF(OFF_F2), WF(OFF_W3T), WF(OFF_F3));
    pool_k<<<144, TPB, 0, stream>>>(WF(OFF_F3), WI(OFF_IDX), WI(OFF_COUNTS) + 48, WF(OFF_POOLED));

    // content CNN
    wtr_k<<<7, TPB, 0, stream>>>(c_w1, WF(OFF_W1T), 64, 27);
    wtr_k<<<72, TPB, 0, stream>>>(c_w2, WF(OFF_W2T), 32, 576);
    wtr_k<<<18, TPB, 0, stream>>>(c_w3, WF(OFF_W3T), 16, 288);
    conv1_k<<<dim3(1024, 2), TPB, 0, stream>>>(content, WF(OFF_W1T), c_b1, WF(OFF_F1));
    f2init_k<<<256, TPB, 0, stream>>>(c_b2, WF(OFF_F2));
    conv2p_k<<<dim3(256, 4), TPB, 0, stream>>>(WF(OFF_F1), WF(OFF_W2T), WF(OFF_F2));
    relu2_k<<<2048, TPB, 0, stream>>>(WF(OFF_F2));
    f3init_k<<<64, TPB, 0, stream>>>(c_b3, WF(OFF_F3));
    conv3p_k<<<dim3(64, 4), TPB, 0, stream>>>(WF(OFF_F2), WF(OFF_W3T), WF(OFF_F3));
    pool_k<<<144, TPB, 0, stream>>>(WF(OFF_F3), WI(OFF_IDX) + 9 * 16384, WI(OFF_COUNTS) + 32,
                                    WF(OFF_POOLED) + 9 * 4096);

    fc_k<<<dim3(4096, 2), TPB, 0, stream>>>(s_fcw, s_fcb, c_fcw, c_fcb, WF(OFF_POOLED), WF(OFF_M));

    uprep1_k<<<576, TPB, 0, stream>>>(unzip_w, WF(OFF_M), WF(OFF_P));
    uprep2_k<<<640, TPB, 0, stream>>>(unzip_w, WF(OFF_M), WF(OFF_P), WF(OFF_U));
    uprep3_k<<<10, TPB, 0, stream>>>(WF(OFF_U), WF(OFF_MU), unzip_b, WF(OFF_SMEAN), WF(OFF_V));

    // final GEMM into rank-compacted Yc (reuses F1/F2 space), then dense merge
    ygemm_k<<<dim3(2560, 4), TPB, 0, stream>>>(WF(OFF_XCT), WF(OFF_U), WF(OFF_V),
                                               WI(OFF_LCNT), WI(OFF_RBASE), WI(OFF_RLIST), WF(OFF_YC));
    merge_k<<<dim3(256, 64), TPB, 0, stream>>>(WF(OFF_YC), WI(OFF_INV), out);
}

// Round 4
// 999.438 us; speedup vs baseline: 1.1628x; 1.1628x over previous
//
#include <hip/hip_runtime.h>
#include <math.h>

#define TPB 256
constexpr int YC_STRIDE = 68096;  // 65536 + 10*256 region padding

// ---------------- workspace layout (bytes) ----------------
constexpr size_t OFF_COUNTS   = 0x000000; // 64 ints
constexpr size_t OFF_ACTIVE   = 0x000100; // 1 int
constexpr size_t OFF_LCNT     = 0x000140; // 10 ints
constexpr size_t OFF_RBASE    = 0x000180; // 10 ints
constexpr size_t OFF_MUSUM    = 0x000200; // 64 floats
constexpr size_t OFF_MU       = 0x000400; // 64 floats
constexpr size_t OFF_SSUM     = 0x000800; // float [4][9][256] partials
constexpr size_t OFF_SMEAN    = 0x00A000; // float [10][256]
constexpr size_t OFF_W1T      = 0x00D000; // [27][64]
constexpr size_t OFF_W3T      = 0x00F000; // [288][16]
constexpr size_t OFF_W2T      = 0x014000; // [576][32]
constexpr size_t OFF_CWT      = 0x028000; // [256][64]  compress_w^T
constexpr size_t OFF_POOLED   = 0x040000; // float [2][9][4096]
constexpr size_t OFF_M        = 0x090000; // float [2][9][4096]
constexpr size_t OFF_P        = 0x0E0000; // float [9][256][64]
constexpr size_t OFF_U        = 0x180000; // float [10][256][64]
constexpr size_t OFF_V        = 0x228000; // float [10][256]
constexpr size_t OFF_CBITS    = 0x230000; // int[65536]
constexpr size_t OFF_SBITS    = 0x270000; // int[65536]
constexpr size_t OFF_CBITS128 = 0x2B0000; // int[16384]
constexpr size_t OFF_SBITS128 = 0x2C0000; // int[16384]
constexpr size_t OFF_IDX      = 0x2D0000; // int [2][9][16384]
constexpr size_t OFF_BC       = 0x3F8000; // int [256][10]
constexpr size_t OFF_BBASE    = 0x400000; // int [256][10]
constexpr size_t OFF_RLIST    = 0x410000; // int [YC_STRIDE]
constexpr size_t OFF_INV      = 0x460000; // int [65536]
constexpr size_t OFF_XCT      = 0x700000; // float [65536][64]  Xc^T
constexpr size_t OFF_F1       = 0x1700000; // float [64][512][512]
constexpr size_t OFF_F2       = 0x5700000; // float [32][256][256]
constexpr size_t OFF_F3       = 0x5F00000; // float [16][128][128]
constexpr size_t OFF_YC       = OFF_F1;    // float [256][YC_STRIDE] (reuses dead F1+F2)

__global__ void init_k(int* p, int n) {
    for (int i = blockIdx.x * TPB + threadIdx.x; i < n; i += gridDim.x * TPB) p[i] = 0;
}

// ---------------- mask bit planes + counts ----------------
__global__ void bits_k(const int* __restrict__ cm, const int* __restrict__ sm,
                       int* __restrict__ cbits, int* __restrict__ sbits, int* __restrict__ counts) {
    int p = blockIdx.x * TPB + threadIdx.x;
    int cb = 0, sb = 0;
#pragma unroll
    for (int r = 0; r < 9; ++r) {
        cb |= (cm[r * 65536 + p] == 1) << r;
        sb |= (sm[r * 65536 + p] == 1) << r;
    }
    cbits[p] = cb; sbits[p] = sb;
    int lane = threadIdx.x & 63;
#pragma unroll
    for (int r = 0; r < 9; ++r) {
        unsigned long long b1 = __ballot((cb >> r) & 1);
        if (lane == 0) atomicAdd(&counts[0 + r], __popcll(b1));
        unsigned long long b2 = __ballot((sb >> r) & 1);
        if (lane == 0) atomicAdd(&counts[16 + r], __popcll(b2));
    }
}

__global__ void bits128_k(const int* __restrict__ cm, const int* __restrict__ sm,
                          int* __restrict__ cbits128, int* __restrict__ sbits128, int* __restrict__ counts) {
    int p = blockIdx.x * TPB + threadIdx.x;
    int y = p >> 7, x = p & 127;
    int src = (2 * y) * 256 + 2 * x;
    int cb = 0, sb = 0;
#pragma unroll
    for (int r = 0; r < 9; ++r) {
        cb |= (cm[r * 65536 + src] == 1) << r;
        sb |= (sm[r * 65536 + src] == 1) << r;
    }
    cbits128[p] = cb; sbits128[p] = sb;
    int lane = threadIdx.x & 63;
#pragma unroll
    for (int r = 0; r < 9; ++r) {
        unsigned long long b1 = __ballot((cb >> r) & 1);
        if (lane == 0) atomicAdd(&counts[32 + r], __popcll(b1));
        unsigned long long b2 = __ballot((sb >> r) & 1);
        if (lane == 0) atomicAdd(&counts[48 + r], __popcll(b2));
    }
}

// ---------------- ordered compaction at 128x128 (ballot scan, 2 barriers/chunk) -----
__global__ void compact_k(const int* __restrict__ sbits128, const int* __restrict__ cbits128,
                          int* __restrict__ idxlist) {
    int r = blockIdx.x, side = blockIdx.y;
    const int* bits = side ? cbits128 : sbits128;
    int* outp = idxlist + (side * 9 + r) * 16384;
    __shared__ int wcnt[4];
    __shared__ int base_s;
    int t = threadIdx.x, w = t >> 6, lane = t & 63;
    if (t == 0) base_s = 0;
    __syncthreads();
    for (int chunk = 0; chunk < 64; ++chunk) {
        int pid = chunk * 256 + t;
        int flag = (bits[pid] >> r) & 1;
        unsigned long long m = __ballot(flag);
        if (lane == 0) wcnt[w] = __popcll(m);
        __syncthreads();
        int base = base_s;
        int woff = 0;
        for (int w2 = 0; w2 < w; ++w2) woff += wcnt[w2];
        if (flag) outp[base + woff + __popcll(m & ((1ull << lane) - 1ull))] = pid;
        __syncthreads();
        if (t == 0) base_s = base + wcnt[0] + wcnt[1] + wcnt[2] + wcnt[3];
    }
}

// ---------------- weight transpose [oc][ick] -> [ick][oc] ----------------
__global__ void wtr_k(const float* __restrict__ w, float* __restrict__ wT, int OC, int ICK) {
    int i = blockIdx.x * TPB + threadIdx.x;
    int n = OC * ICK;
    if (i < n) {
        int oc = i / ICK;
        int t = i - oc * ICK;
        wT[t * OC + oc] = w[i];
    }
}

// ---------------- per-region style mean partial sums ----------------
__global__ void smean_k(const float* __restrict__ sF, const int* __restrict__ sbits,
                        float* __restrict__ ssump) {
    int c = blockIdx.x;
    int pg = blockIdx.y;
    int t = threadIdx.x;
    float acc[9];
#pragma unroll
    for (int r = 0; r < 9; ++r) acc[r] = 0.f;
    int p0 = pg * 16384;
    for (int p = p0 + t; p < p0 + 16384; p += TPB) {
        float v = sF[c * 65536 + p];
        int b = sbits[p];
#pragma unroll
        for (int r = 0; r < 9; ++r)
            if (b & (1 << r)) acc[r] += v;
    }
    __shared__ float red[9 * TPB];
#pragma unroll
    for (int r = 0; r < 9; ++r) red[r * TPB + t] = acc[r];
    __syncthreads();
    for (int off = TPB / 2; off > 0; off >>= 1) {
        if (t < off)
#pragma unroll
            for (int r = 0; r < 9; ++r) red[r * TPB + t] += red[r * TPB + t + off];
        __syncthreads();
    }
    if (t < 9) ssump[(pg * 9 + t) * 256 + c] = red[t * TPB];
}

// ---------------- active mask + per-region style means ----------------
__global__ void finalize_k(const int* __restrict__ counts, int* __restrict__ activemask,
                           const float* __restrict__ ssump, float* __restrict__ sMeanArr) {
    __shared__ int am;
    if (threadIdx.x == 0) am = 0;
    __syncthreads();
    if (threadIdx.x < 9) {
        int r = threadIdx.x;
        if (counts[0 + r] >= 10 && counts[16 + r] >= 10 && counts[32 + r] >= 10 && counts[48 + r] >= 10)
            atomicOr(&am, 1 << r);
    }
    __syncthreads();
    if (threadIdx.x == 0) *activemask = am;
    for (int e = threadIdx.x; e < 2560; e += TPB) {
        int r = e >> 8, c = e & 255;
        float v = 0.f;
        if (r < 9 && ((am >> r) & 1)) {
            float s = ssump[(0 * 9 + r) * 256 + c] + ssump[(1 * 9 + r) * 256 + c]
                    + ssump[(2 * 9 + r) * 256 + c] + ssump[(3 * 9 + r) * 256 + c];
            v = s / (float)counts[16 + r];
        }
        sMeanArr[e] = v;
    }
}

// ---------------- stable region ranking at 256-res: hist -> scan -> rank -------------
__global__ void hist_k(const int* __restrict__ cbits, const int* __restrict__ activemask,
                       int* __restrict__ rmap, int* __restrict__ bc) {
    int b = blockIdx.x, t = threadIdx.x;
    int p = b * 256 + t;
    int am = *activemask;
    int bits = cbits[p] & am;
    int r = bits ? (31 - __clz(bits)) : 9;
    rmap[p] = r;
    __shared__ int wc[4][10];
    int w = t >> 6, lane = t & 63;
#pragma unroll
    for (int rr = 0; rr < 10; ++rr) {
        unsigned long long m = __ballot(r == rr);
        if (lane == rr) wc[w][rr] = __popcll(m);
    }
    __syncthreads();
    if (t < 10) bc[b * 10 + t] = wc[0][t] + wc[1][t] + wc[2][t] + wc[3][t];
}

__global__ void scan_k(const int* __restrict__ bc, int* __restrict__ bbase,
                       int* __restrict__ lcnt, int* __restrict__ rbase) {
    __shared__ int tot[10], Bs[16];
    int t = threadIdx.x;
    if (t < 10) {
        int s = 0;
        for (int b = 0; b < 256; ++b) s += bc[b * 10 + t];
        tot[t] = s;
    }
    __syncthreads();
    if (t == 0) {
        int run = 0;
        for (int r = 0; r < 10; ++r) { Bs[r] = run; run += (tot[r] + 255) & ~255; }
    }
    __syncthreads();
    if (t < 10) {
        lcnt[t] = tot[t];
        rbase[t] = Bs[t];
        int run = Bs[t];
        for (int b = 0; b < 256; ++b) { bbase[b * 10 + t] = run; run += bc[b * 10 + t]; }
    }
}

__global__ void rank_k(const int* __restrict__ rmap, const int* __restrict__ bbase,
                       int* __restrict__ inv, int* __restrict__ rlist) {
    int b = blockIdx.x, t = threadIdx.x;
    int p = b * 256 + t;
    int r = rmap[p];
    __shared__ int wc[4][10];
    int w = t >> 6, lane = t & 63;
    int prefix = 0;
#pragma unroll
    for (int rr = 0; rr < 10; ++rr) {
        unsigned long long m = __ballot(r == rr);
        if (rr == r) prefix = __popcll(m & ((1ull << lane) - 1ull));
        if (lane == rr) wc[w][rr] = __popcll(m);
    }
    __syncthreads();
    int woff = 0;
    for (int w2 = 0; w2 < w; ++w2) woff += wc[w2][r];
    int g = bbase[b * 10 + r] + woff + prefix;
    inv[p] = g;
    rlist[g] = p;
}

// ---------------- helpers for 4px x 8oc conv tiling ----------------
__device__ __forceinline__ void ld8(float* d, const float* __restrict__ p) {
    float4 a = *(const float4*)p;
    float4 b = *(const float4*)(p + 4);
    d[0] = a.x; d[1] = a.y; d[2] = a.z; d[3] = a.w;
    d[4] = b.x; d[5] = b.y; d[6] = b.z; d[7] = b.w;
}

// ---------------- conv1: 1024x1024x3 -> 512x512x64, LDS ev/od, 4px x 8oc ----------
// block = half an output row (256 px); og32-split 2. Thread t: px group g=t&63
// (pixels 4g..4g+3), oc group og=t>>6 (8 ocs). Weight loads wave-uniform.
__global__ void conv1_k(const float* __restrict__ in, const float* __restrict__ wT,
                        const float* __restrict__ b, float* __restrict__ out) {
    int oy = blockIdx.x >> 1;
    int X0 = (blockIdx.x & 1) << 8;    // 0 or 256
    int og32 = blockIdx.y;
    int t = threadIdx.x;
    int g = t & 63;
    int og = __builtin_amdgcn_readfirstlane(t >> 6);   // wave-uniform 8-oc group
    __shared__ float ev[3][3][260];
    __shared__ float od[3][3][264];
    // stage interior: 3 ic x 3 rows x 128 float4 (coalesced), de-interleaved into ev/od
    for (int u = t; u < 1152; u += 256) {
        int ic = u / 384;
        int rem = u - ic * 384;
        int row = rem >> 7, q = rem & 127;
        int iy = 2 * oy - 1 + row;
        float4 v = make_float4(0.f, 0.f, 0.f, 0.f);
        if ((unsigned)iy < 1024u)
            v = *(const float4*)(in + ic * 1048576 + iy * 1024 + 2 * X0 + 4 * q);
        ev[ic][row][2 * q]     = v.x;   // x=4q
        od[ic][row][2 * q + 1] = v.y;   // x=4q+1
        ev[ic][row][2 * q + 1] = v.z;   // x=4q+2
        od[ic][row][2 * q + 2] = v.w;   // x=4q+3
    }
    // left halo (x = -1, i.e. ix = 2*X0 - 1)
    if (t < 9) {
        int ic = t / 3, row = t % 3;
        int iy = 2 * oy - 1 + row;
        int ix = 2 * X0 - 1;
        float v = 0.f;
        if ((unsigned)iy < 1024u && ix >= 0) v = in[ic * 1048576 + iy * 1024 + ix];
        od[ic][row][0] = v;
    }
    __syncthreads();
    int ocb = og32 * 32 + og * 8;
    float bias[8];
    ld8(bias, b + ocb);
    float acc[4][8];
#pragma unroll
    for (int j = 0; j < 4; ++j)
#pragma unroll
        for (int c = 0; c < 8; ++c) acc[j][c] = bias[c];
#pragma unroll
    for (int ic = 0; ic < 3; ++ic)
#pragma unroll
        for (int ky = 0; ky < 3; ++ky) {
            float4 e4 = *(const float4*)&ev[ic][ky][4 * g];
            float4 o4 = *(const float4*)&od[ic][ky][4 * g];
            float  o5 = od[ic][ky][4 * g + 4];
            float e_[4] = {e4.x, e4.y, e4.z, e4.w};
            float o_[5] = {o4.x, o4.y, o4.z, o4.w, o5};
            const float* wbase = wT + (ic * 9 + ky * 3) * 64 + ocb;
            float wA[8], wB[8], wC[8];
            ld8(wA, wbase);            // kx = 0
            ld8(wB, wbase + 64);       // kx = 1
            ld8(wC, wbase + 128);      // kx = 2
#pragma unroll
            for (int j = 0; j < 4; ++j) {
                float v0 = o_[j], v1 = e_[j], v2 = o_[j + 1];
#pragma unroll
                for (int c = 0; c < 8; ++c)
                    acc[j][c] = fmaf(wA[c], v0, fmaf(wB[c], v1, fmaf(wC[c], v2, acc[j][c])));
            }
        }
    int idx = oy * 512 + X0 + 4 * g;
#pragma unroll
    for (int c = 0; c < 8; ++c) {
        float4 o = make_float4(fmaxf(acc[0][c], 0.f), fmaxf(acc[1][c], 0.f),
                               fmaxf(acc[2][c], 0.f), fmaxf(acc[3][c], 0.f));
        *(float4*)(out + (size_t)(ocb + c) * 262144 + idx) = o;
    }
}

// ---------------- conv2: bias init, ic-split-4 atomic partials, relu ----------------
__global__ void f2init_k(const float* __restrict__ b, float* __restrict__ F2) {
    int idx = blockIdx.x * TPB + threadIdx.x;
#pragma unroll
    for (int oc = 0; oc < 32; ++oc) F2[oc * 65536 + idx] = b[oc];
}

// conv2: block = one output row (256 px), STRIDED 4px x 8oc per thread
// (thread lane g owns pixels g, g+64, g+128, g+192 -> epilogue atomics are
// lane-dense/coalesced; LDS reads are stride-1 scalar = conflict-free).
// Double-buffered ev/od LDS tile, async-STAGE split.
__device__ __forceinline__ void c2_load(const float* __restrict__ base, int oy, int t,
                                        float4& r0, float4& r1) {
    int row0 = t >> 7, q0 = t & 127;     // rows 0,1
    int iy0 = 2 * oy - 1 + row0;
    r0 = make_float4(0.f, 0.f, 0.f, 0.f);
    if ((unsigned)iy0 < 512u) r0 = *(const float4*)(base + iy0 * 512 + 4 * q0);
    r1 = make_float4(0.f, 0.f, 0.f, 0.f);
    if (t < 128) {                        // row 2: iy = 2*oy+1, always in range
        int iy1 = 2 * oy + 1;
        r1 = *(const float4*)(base + iy1 * 512 + 4 * t);
    }
}

__device__ __forceinline__ void c2_store(float (*ev)[260], float (*od)[264], int t,
                                         float4 r0, float4 r1) {
    int row0 = t >> 7, q0 = t & 127;
    ev[row0][2 * q0]     = r0.x;   // x=4q
    od[row0][2 * q0 + 1] = r0.y;   // x=4q+1
    ev[row0][2 * q0 + 1] = r0.z;   // x=4q+2
    od[row0][2 * q0 + 2] = r0.w;   // x=4q+3
    if (t < 128) {
        ev[2][2 * t]     = r1.x;
        od[2][2 * t + 1] = r1.y;
        ev[2][2 * t + 1] = r1.z;
        od[2][2 * t + 2] = r1.w;
    }
}

__device__ __forceinline__ void c2_compute(const float* __restrict__ wT, int ic,
                                           const float (*ev)[260], const float (*od)[264],
                                           int g, int og, float (*acc)[8]) {
#pragma unroll
    for (int ky = 0; ky < 3; ++ky) {
        const float* wbase = wT + (ic * 9 + ky * 3) * 32 + og * 8;
        float wA[8], wB[8], wC[8];
        ld8(wA, wbase);           // kx = 0
        ld8(wB, wbase + 32);      // kx = 1
        ld8(wC, wbase + 64);      // kx = 2
#pragma unroll
        for (int j = 0; j < 4; ++j) {
            int ox = g + 64 * j;
            float v0 = od[ky][ox];       // x = 2*ox-1  (kx=0)
            float v1 = ev[ky][ox];       // x = 2*ox    (kx=1)
            float v2 = od[ky][ox + 1];   // x = 2*ox+1  (kx=2) -> ds_read2 with v0
#pragma unroll
            for (int c = 0; c < 8; ++c)
                acc[j][c] = fmaf(wA[c], v0, fmaf(wB[c], v1, fmaf(wC[c], v2, acc[j][c])));
        }
    }
}

__global__ void conv2p_k(const float* __restrict__ in, const float* __restrict__ wT,
                         float* __restrict__ F2) {
    int oy = blockIdx.x;      // 0..255
    int icg = blockIdx.y;     // 0..3
    int t = threadIdx.x;
    int g = t & 63;
    int og = __builtin_amdgcn_readfirstlane(t >> 6);   // wave-uniform 8-oc group
    __shared__ float ev[2][3][260];
    __shared__ float od[2][3][264];
    if (t < 6) od[t / 3][t % 3][0] = 0.f;   // left halo (x = -1) stays zero, both buffers
    float acc[4][8];
#pragma unroll
    for (int j = 0; j < 4; ++j)
#pragma unroll
        for (int c = 0; c < 8; ++c) acc[j][c] = 0.f;
    int ic0 = icg * 16;
    float4 r0, r1;
    c2_load(in + ic0 * 262144, oy, t, r0, r1);
    c2_store(ev[0], od[0], t, r0, r1);
    __syncthreads();
#pragma unroll 1
    for (int i = 0; i < 16; i += 2) {
        c2_load(in + (ic0 + i + 1) * 262144, oy, t, r0, r1);   // issue loads early
        c2_compute(wT, ic0 + i, ev[0], od[0], g, og, acc);     // hide latency under FMAs
        c2_store(ev[1], od[1], t, r0, r1);                     // vmcnt drained after compute
        __syncthreads();
        if (i + 2 < 16) c2_load(in + (ic0 + i + 2) * 262144, oy, t, r0, r1);
        c2_compute(wT, ic0 + i + 1, ev[1], od[1], g, og, acc);
        if (i + 2 < 16) c2_store(ev[0], od[0], t, r0, r1);
        __syncthreads();
    }
    int rowbase = oy * 256;
#pragma unroll
    for (int c = 0; c < 8; ++c)
#pragma unroll
        for (int j = 0; j < 4; ++j)
            atomicAdd(&F2[(og * 8 + c) * 65536 + rowbase + 64 * j + g], acc[j][c]);
}

__global__ void relu2_k(float* __restrict__ F2) {
    int i = blockIdx.x * TPB + threadIdx.x;
    float4* p = (float4*)F2;
    float4 v = p[i];
    v.x = fmaxf(v.x, 0.f); v.y = fmaxf(v.y, 0.f);
    v.z = fmaxf(v.z, 0.f); v.w = fmaxf(v.w, 0.f);
    p[i] = v;
}

// ---------------- conv3: bias init + ic-split-4 atomic partials (no relu) ------------
__global__ void f3init_k(const float* __restrict__ b, float* __restrict__ F3) {
    int idx = blockIdx.x * TPB + threadIdx.x;
#pragma unroll
    for (int oc = 0; oc < 16; ++oc) F3[oc * 16384 + idx] = b[oc];
}

__global__ void conv3p_k(const float* __restrict__ in, const float* __restrict__ wT,
                         float* __restrict__ F3) {
    int idx = blockIdx.x * TPB + threadIdx.x;
    int icg = blockIdx.y;
    int ox = idx & 127, oy = idx >> 7;
    float acc[16];
#pragma unroll
    for (int oc = 0; oc < 16; ++oc) acc[oc] = 0.f;
    for (int ic = icg * 8; ic < icg * 8 + 8; ++ic) {
        const float* base = in + ic * 65536;
#pragma unroll
        for (int ky = 0; ky < 3; ++ky) {
            int iy = 2 * oy - 1 + ky;
            if ((unsigned)iy < 256u)
#pragma unroll
                for (int kx = 0; kx < 3; ++kx) {
                    int ix = 2 * ox - 1 + kx;
                    if ((unsigned)ix < 256u) {
                        float v = base[iy * 256 + ix];
                        const float4* wp = (const float4*)(wT + (ic * 9 + ky * 3 + kx) * 16);
#pragma unroll
                        for (int q = 0; q < 4; ++q) {
                            float4 w4 = wp[q];
                            acc[q * 4 + 0] = fmaf(w4.x, v, acc[q * 4 + 0]);
                            acc[q * 4 + 1] = fmaf(w4.y, v, acc[q * 4 + 1]);
                            acc[q * 4 + 2] = fmaf(w4.z, v, acc[q * 4 + 2]);
                            acc[q * 4 + 3] = fmaf(w4.w, v, acc[q * 4 + 3]);
                        }
                    }
                }
        }
    }
#pragma unroll
    for (int oc = 0; oc < 16; ++oc) atomicAdd(&F3[oc * 16384 + idx], acc[oc]);
}

// ---------------- adaptive max pool over ordered compacted indices ----------------
__global__ void pool_k(const float* __restrict__ f3, const int* __restrict__ idxbase,
                       const int* __restrict__ cnt, float* __restrict__ pooled) {
    int r = blockIdx.x >> 4;
    int c = blockIdx.x & 15;
    int j = threadIdx.x;
    int n = cnt[r];
    float m = 0.f;
    if (n >= 1) {
        int start = (j * n) >> 8;
        int end = ((j + 1) * n + 255) >> 8;
        const int* il = idxbase + r * 16384;
        m = -__builtin_inff();
        for (int t = start; t < end; ++t) m = fmaxf(m, f3[c * 16384 + il[t]]);
    }
    pooled[(r * 16 + c) * 256 + j] = m;
}

// ---------------- FC: M[side][r][row] (9 cols batched per row-block) ----------------
__global__ void fc_k(const float* __restrict__ fcw_s, const float* __restrict__ fcb_s,
                     const float* __restrict__ fcw_c, const float* __restrict__ fcb_c,
                     const float* __restrict__ pooled, float* __restrict__ Mout) {
    int row = blockIdx.x;
    int side = blockIdx.y;
    const float* fcw = side ? fcw_c : fcw_s;
    const float* fcb = side ? fcb_c : fcb_s;
    const float* P = pooled + side * 9 * 4096;
    int t = threadIdx.x;
    float acc[9];
#pragma unroll
    for (int r = 0; r < 9; ++r) acc[r] = 0.f;
    for (int k = t; k < 4096; k += TPB) {
        float w = fcw[row * 4096 + k];
#pragma unroll
        for (int r = 0; r < 9; ++r) acc[r] = fmaf(w, P[r * 4096 + k], acc[r]);
    }
    __shared__ float red[9 * TPB];
#pragma unroll
    for (int r = 0; r < 9; ++r) red[r * TPB + t] = acc[r];
    __syncthreads();
    for (int off = TPB / 2; off > 0; off >>= 1) {
        if (t < off)
#pragma unroll
            for (int r = 0; r < 9; ++r) red[r * TPB + t] += red[r * TPB + t + off];
        __syncthreads();
    }
    if (t < 9) Mout[(side * 9 + t) * 4096 + row] = red[t * TPB] + fcb[row];
}

// ---------------- Xc^T = (compress_w @ cF)^T, m-split 4 ----------------
__global__ void xgemm_k(const float* __restrict__ cF, const float* __restrict__ cwT,
                        float* __restrict__ XcT) {
    int p = blockIdx.x * TPB + threadIdx.x;
    int m0 = blockIdx.y * 16;
    float acc[16];
#pragma unroll
    for (int m = 0; m < 16; ++m) acc[m] = 0.f;
    for (int k0 = 0; k0 < 256; k0 += 4) {
        float xv[4];
#pragma unroll
        for (int i = 0; i < 4; ++i) xv[i] = cF[(k0 + i) * 65536 + p];
#pragma unroll
        for (int i = 0; i < 4; ++i) {
            const float4* wp = (const float4*)(cwT + (k0 + i) * 64 + m0);
#pragma unroll
            for (int q = 0; q < 4; ++q) {
                float4 w4 = wp[q];
                acc[q * 4 + 0] = fmaf(w4.x, xv[i], acc[q * 4 + 0]);
                acc[q * 4 + 1] = fmaf(w4.y, xv[i], acc[q * 4 + 1]);
                acc[q * 4 + 2] = fmaf(w4.z, xv[i], acc[q * 4 + 2]);
                acc[q * 4 + 3] = fmaf(w4.w, xv[i], acc[q * 4 + 3]);
            }
        }
    }
    float4* op = (float4*)(XcT + p * 64 + m0);
#pragma unroll
    for (int q = 0; q < 4; ++q)
        op[q] = make_float4(acc[q * 4 + 0], acc[q * 4 + 1], acc[q * 4 + 2], acc[q * 4 + 3]);
}

// ---------------- mu from Xc^T ----------------
__global__ void muacc_k(const float* __restrict__ XcT, float* __restrict__ musum) {
    int t = threadIdx.x;
    int m = t & 63, sub = t >> 6;
    int p0 = blockIdx.x * 256;
    float a = 0.f;
    for (int i = 0; i < 64; ++i) a += XcT[(p0 + sub + i * 4) * 64 + m];
    __shared__ float red[TPB];
    red[t] = a;
    __syncthreads();
    if (t < 64) atomicAdd(&musum[t], red[t] + red[t + 64] + red[t + 128] + red[t + 192]);
}

__global__ void mufin_k(const float* __restrict__ musum, float* __restrict__ mu) {
    int t = threadIdx.x;
    if (t < 64) mu[t] = musum[t] * (1.f / 65536.f);
}

// ---------------- U/V precompute ----------------
__global__ void uprep1_k(const float* __restrict__ uw, const float* __restrict__ M,
                         float* __restrict__ P) {
    int idx = blockIdx.x * TPB + threadIdx.x;
    int r = idx / 16384;
    int rem = idx & 16383;
    int c = rem >> 6, k = rem & 63;
    float a = 0.f;
#pragma unroll 8
    for (int i = 0; i < 64; ++i) a = fmaf(uw[c * 64 + i], M[r * 4096 + i * 64 + k], a);
    P[idx] = a;
}

__global__ void uprep2_k(const float* __restrict__ uw, const float* __restrict__ M,
                         const float* __restrict__ P, float* __restrict__ U) {
    int idx = blockIdx.x * TPB + threadIdx.x;
    int r = idx / 16384;
    int rem = idx & 16383;
    int c = rem >> 6, j = rem & 63;
    if (r == 9) { U[idx] = uw[c * 64 + j]; return; }
    float a = 0.f;
#pragma unroll 8
    for (int k = 0; k < 64; ++k) a = fmaf(P[r * 16384 + c * 64 + k], M[(9 + r) * 4096 + k * 64 + j], a);
    U[idx] = a;
}

__global__ void uprep3_k(const float* __restrict__ U, const float* __restrict__ mu,
                         const float* __restrict__ uzb, const float* __restrict__ sMeanArr,
                         float* __restrict__ V) {
    int r = blockIdx.x;
    int c = threadIdx.x;
    float a = uzb[c] + sMeanArr[r * 256 + c];
#pragma unroll 8
    for (int j = 0; j < 64; ++j) a -= U[r * 16384 + c * 64 + j] * mu[j];
    V[r * 256 + c] = a;
}

// ---------------- Yc[oc][rank] = U_r @ Xc + V_r  (coalesced full-line writes) --------
__global__ void ygemm_k(const float* __restrict__ XcT, const float* __restrict__ U,
                        const float* __restrict__ V, const int* __restrict__ lcnt,
                        const int* __restrict__ rbase, const int* __restrict__ rlist,
                        float* __restrict__ Yc) {
    int r = blockIdx.x >> 8;
    int c = blockIdx.x & 255;
    int ocg = blockIdx.y;
    int n = lcnt[r];
    int start = c * 256;
    if (start >= n) return;
    int i = start + threadIdx.x;
    bool valid = i < n;
    int gi = rbase[r] + (valid ? i : n - 1);
    int pix = rlist[gi];
    float4 xv[16];
    const float4* xp = (const float4*)(XcT + (size_t)pix * 64);
#pragma unroll
    for (int q = 0; q < 16; ++q) xv[q] = xp[q];
    const float* Ur = U + r * 16384 + ocg * 4096;
    const float* Vr = V + r * 256 + ocg * 64;
#pragma unroll 4
    for (int oc = 0; oc < 64; ++oc) {
        float a = Vr[oc];
        const float4* up = (const float4*)(Ur + oc * 64);
#pragma unroll
        for (int q = 0; q < 16; ++q) {
            float4 u4 = up[q];
            a = fmaf(u4.x, xv[q].x, a);
            a = fmaf(u4.y, xv[q].y, a);
            a = fmaf(u4.z, xv[q].z, a);
            a = fmaf(u4.w, xv[q].w, a);
        }
        if (valid) Yc[(size_t)(ocg * 64 + oc) * YC_STRIDE + gi] = a;   // store now: no acc[], no spill
    }
}

// ---------------- merge: out[oc][p] = Yc[oc][inv[p]]  (coalesced output writes) ------
__global__ void merge_k(const float* __restrict__ Yc, const int* __restrict__ inv,
                        float* __restrict__ out) {
    int p = blockIdx.x * TPB + threadIdx.x;
    int oc0 = blockIdx.y * 4;
    int gi = inv[p];
#pragma unroll
    for (int j = 0; j < 4; ++j)
        out[(size_t)(oc0 + j) * 65536 + p] = Yc[(size_t)(oc0 + j) * YC_STRIDE + gi];
}

// ---------------- launch ----------------
extern "C" void kernel_launch(void* const* d_in, const int* in_sizes, int n_in,
                              void* d_out, int out_size, void* d_ws, size_t ws_size,
                              hipStream_t stream) {
    const float* cF         = (const float*)d_in[0];
    const float* sF         = (const float*)d_in[1];
    const float* content    = (const float*)d_in[2];
    const float* style      = (const float*)d_in[3];
    const int*   cmasks     = (const int*)d_in[4];
    const int*   smasks     = (const int*)d_in[5];
    const float* compress_w = (const float*)d_in[6];
    const float* unzip_w    = (const float*)d_in[8];
    const float* unzip_b    = (const float*)d_in[9];
    const float* s_w1 = (const float*)d_in[10]; const float* s_b1 = (const float*)d_in[11];
    const float* s_w2 = (const float*)d_in[12]; const float* s_b2 = (const float*)d_in[13];
    const float* s_w3 = (const float*)d_in[14]; const float* s_b3 = (const float*)d_in[15];
    const float* s_fcw = (const float*)d_in[16]; const float* s_fcb = (const float*)d_in[17];
    const float* c_w1 = (const float*)d_in[18]; const float* c_b1 = (const float*)d_in[19];
    const float* c_w2 = (const float*)d_in[20]; const float* c_b2 = (const float*)d_in[21];
    const float* c_w3 = (const float*)d_in[22]; const float* c_b3 = (const float*)d_in[23];
    const float* c_fcw = (const float*)d_in[24]; const float* c_fcb = (const float*)d_in[25];
    float* out = (float*)d_out;
    char* ws = (char*)d_ws;
#define WF(o) ((float*)(ws + (o)))
#define WI(o) ((int*)(ws + (o)))

    init_k<<<1, TPB, 0, stream>>>(WI(0), 256);   // counts, active, musum
    bits_k<<<256, TPB, 0, stream>>>(cmasks, smasks, WI(OFF_CBITS), WI(OFF_SBITS), WI(OFF_COUNTS));
    bits128_k<<<64, TPB, 0, stream>>>(cmasks, smasks, WI(OFF_CBITS128), WI(OFF_SBITS128), WI(OFF_COUNTS));
    compact_k<<<dim3(9, 2), TPB, 0, stream>>>(WI(OFF_SBITS128), WI(OFF_CBITS128), WI(OFF_IDX));
    smean_k<<<dim3(256, 4), TPB, 0, stream>>>(sF, WI(OFF_SBITS), WF(OFF_SSUM));
    finalize_k<<<1, TPB, 0, stream>>>(WI(OFF_COUNTS), WI(OFF_ACTIVE), WF(OFF_SSUM), WF(OFF_SMEAN));

    // stable region ranking
    hist_k<<<256, TPB, 0, stream>>>(WI(OFF_CBITS), WI(OFF_ACTIVE), WI(OFF_INV) /*tmp rmap*/, WI(OFF_BC));
    scan_k<<<1, TPB, 0, stream>>>(WI(OFF_BC), WI(OFF_BBASE), WI(OFF_LCNT), WI(OFF_RBASE));
    rank_k<<<256, TPB, 0, stream>>>(WI(OFF_INV) /*rmap in*/, WI(OFF_BBASE), WI(OFF_INV), WI(OFF_RLIST));

    // Xc^T (compress)
    wtr_k<<<64, TPB, 0, stream>>>(compress_w, WF(OFF_CWT), 64, 256);
    xgemm_k<<<dim3(256, 4), TPB, 0, stream>>>(cF, WF(OFF_CWT), WF(OFF_XCT));
    muacc_k<<<256, TPB, 0, stream>>>(WF(OFF_XCT), WF(OFF_MUSUM));
    mufin_k<<<1, 64, 0, stream>>>(WF(OFF_MUSUM), WF(OFF_MU));

    // style CNN
    wtr_k<<<7, TPB, 0, stream>>>(s_w1, WF(OFF_W1T), 64, 27);
    wtr_k<<<72, TPB, 0, stream>>>(s_w2, WF(OFF_W2T), 32, 576);
    wtr_k<<<18, TPB, 0, stream>>>(s_w3, WF(OFF_W3T), 16, 288);
    conv1_k<<<dim3(1024, 2), TPB, 0, stream>>>(style, WF(OFF_W1T), s_b1, WF(OFF_F1));
    f2init_k<<<256, TPB, 0, stream>>>(s_b2, WF(OFF_F2));
    conv2p_k<<<dim3(256, 4), TPB, 0, stream>>>(WF(OFF_F1), WF(OFF_W2T), WF(OFF_F2));
    relu2_k<<<2048, TPB, 0, stream>>>(WF(OFF_F2));
    f3init_k<<<64, TPB, 0, stream>>>(s_b3, WF(OFF_F3));
    conv3p_k<<<dim3(64, 4), TPB, 0, stream>>>(WF(OFF_F2), WF(OFF_W3T), WF(OFF_F3));
    pool_k<<<144, TPB, 0, stream>>>(WF(OFF_F3), WI(OFF_IDX), WI(OFF_COUNTS) + 48, WF(OFF_POOLED));

    // content CNN
    wtr_k<<<7, TPB, 0, stream>>>(c_w1, WF(OFF_W1T), 64, 27);
    wtr_k<<<72, TPB, 0, stream>>>(c_w2, WF(OFF_W2T), 32, 576);
    wtr_k<<<18, TPB, 0, stream>>>(c_w3, WF(OFF_W3T), 16, 288);
    conv1_k<<<dim3(1024, 2), TPB, 0, stream>>>(content, WF(OFF_W1T), c_b1, WF(OFF_F1));
    f2init_k<<<256, TPB, 0, stream>>>(c_b2, WF(OFF_F2));
    conv2p_k<<<dim3(256, 4), TPB, 0, stream>>>(WF(OFF_F1), WF(OFF_W2T), WF(OFF_F2));
    relu2_k<<<2048, TPB, 0, stream>>>(WF(OFF_F2));
    f3init_k<<<64, TPB, 0, stream>>>(c_b3, WF(OFF_F3));
    conv3p_k<<<dim3(64, 4), TPB, 0, stream>>>(WF(OFF_F2), WF(OFF_W3T), WF(OFF_F3));
    pool_k<<<144, TPB, 0, stream>>>(WF(OFF_F3), WI(OFF_IDX) + 9 * 16384, WI(OFF_COUNTS) + 32,
                                    WF(OFF_POOLED) + 9 * 4096);

    fc_k<<<dim3(4096, 2), TPB, 0, stream>>>(s_fcw, s_fcb, c_fcw, c_fcb, WF(OFF_POOLED), WF(OFF_M));

    uprep1_k<<<576, TPB, 0, stream>>>(unzip_w, WF(OFF_M), WF(OFF_P));
    uprep2_k<<<640, TPB, 0, stream>>>(unzip_w, WF(OFF_M), WF(OFF_P), WF(OFF_U));
    uprep3_k<<<10, TPB, 0, stream>>>(WF(OFF_U), WF(OFF_MU), unzip_b, WF(OFF_SMEAN), WF(OFF_V));

    // final GEMM into rank-compacted Yc (reuses F1/F2 space), then dense merge
    ygemm_k<<<dim3(2560, 4), TPB, 0, stream>>>(WF(OFF_XCT), WF(OFF_U), WF(OFF_V),
                                               WI(OFF_LCNT), WI(OFF_RBASE), WI(OFF_RLIST), WF(OFF_YC));
    merge_k<<<dim3(256, 64), TPB, 0, stream>>>(WF(OFF_YC), WI(OFF_INV), out);
}

// Round 5
// 897.207 us; speedup vs baseline: 1.2953x; 1.1139x over previous
//
#include <hip/hip_runtime.h>
#include <math.h>

#define TPB 256
constexpr int YC_STRIDE = 68096;  // 65536 + 10*256 region padding

// ---------------- workspace layout (bytes) ----------------
constexpr size_t OFF_COUNTS   = 0x000000; // 64 ints
constexpr size_t OFF_ACTIVE   = 0x000100; // 1 int
constexpr size_t OFF_LCNT     = 0x000140; // 10 ints
constexpr size_t OFF_RBASE    = 0x000180; // 10 ints
constexpr size_t OFF_MUSUM    = 0x000200; // 64 floats
constexpr size_t OFF_MU       = 0x000400; // 64 floats
constexpr size_t OFF_SSUM     = 0x000800; // float [4][9][256] partials
constexpr size_t OFF_SMEAN    = 0x00A000; // float [10][256]
constexpr size_t OFF_W1T      = 0x00D000; // [27][64]
constexpr size_t OFF_W3T      = 0x00F000; // [288][16]
constexpr size_t OFF_W2T      = 0x014000; // [576][32]
constexpr size_t OFF_CWT      = 0x028000; // [256][64]  compress_w^T
constexpr size_t OFF_POOLED   = 0x040000; // float [2][9][4096]
constexpr size_t OFF_M        = 0x090000; // float [2][9][4096]
constexpr size_t OFF_P        = 0x0E0000; // float [9][256][64]
constexpr size_t OFF_U        = 0x180000; // float [10][256][64]
constexpr size_t OFF_V        = 0x228000; // float [10][256]
constexpr size_t OFF_CBITS    = 0x230000; // int[65536]
constexpr size_t OFF_SBITS    = 0x270000; // int[65536]
constexpr size_t OFF_CBITS128 = 0x2B0000; // int[16384]
constexpr size_t OFF_SBITS128 = 0x2C0000; // int[16384]
constexpr size_t OFF_IDX      = 0x2D0000; // int [2][9][16384]
constexpr size_t OFF_BC       = 0x3F8000; // int [256][10]
constexpr size_t OFF_BBASE    = 0x400000; // int [256][10]
constexpr size_t OFF_RLIST    = 0x410000; // int [YC_STRIDE]
constexpr size_t OFF_INV      = 0x460000; // int [65536]
constexpr size_t OFF_PC256    = 0x4A0000; // int [256][18] per-block mask popcounts (256-res)
constexpr size_t OFF_PC128    = 0x4A8000; // int [64][18]  per-block mask popcounts (128-res)
constexpr size_t OFF_XCT      = 0x700000; // float [65536][64]  Xc^T
constexpr size_t OFF_F1       = 0x1700000; // float [64][512][512]
constexpr size_t OFF_F2       = 0x5700000; // float [32][256][256]
constexpr size_t OFF_F3       = 0x5F00000; // float [16][128][128]
constexpr size_t OFF_YC       = OFF_F1;    // float [256][YC_STRIDE] (reuses dead F1+F2)

__global__ void init_k(int* p, int n) {
    for (int i = blockIdx.x * TPB + threadIdx.x; i < n; i += gridDim.x * TPB) p[i] = 0;
}

// ---------------- mask bit planes + per-block popcount partials (no atomics) --------
__global__ void bits_k(const int* __restrict__ cm, const int* __restrict__ sm,
                       int* __restrict__ cbits, int* __restrict__ sbits, int* __restrict__ pc) {
    int t = threadIdx.x;
    int p = blockIdx.x * TPB + t;
    int cb = 0, sb = 0;
#pragma unroll
    for (int r = 0; r < 9; ++r) {
        cb |= (cm[r * 65536 + p] == 1) << r;
        sb |= (sm[r * 65536 + p] == 1) << r;
    }
    cbits[p] = cb; sbits[p] = sb;
    __shared__ int wc[4][18];
    int w = t >> 6, lane = t & 63;
#pragma unroll
    for (int r = 0; r < 9; ++r) {
        unsigned long long b1 = __ballot((cb >> r) & 1);
        if (lane == 0) wc[w][r] = __popcll(b1);
        unsigned long long b2 = __ballot((sb >> r) & 1);
        if (lane == 0) wc[w][9 + r] = __popcll(b2);
    }
    __syncthreads();
    if (t < 18) pc[blockIdx.x * 18 + t] = wc[0][t] + wc[1][t] + wc[2][t] + wc[3][t];
}

__global__ void bits128_k(const int* __restrict__ cm, const int* __restrict__ sm,
                          int* __restrict__ cbits128, int* __restrict__ sbits128,
                          int* __restrict__ pc) {
    int t = threadIdx.x;
    int p = blockIdx.x * TPB + t;
    int y = p >> 7, x = p & 127;
    int src = (2 * y) * 256 + 2 * x;
    int cb = 0, sb = 0;
#pragma unroll
    for (int r = 0; r < 9; ++r) {
        cb |= (cm[r * 65536 + src] == 1) << r;
        sb |= (sm[r * 65536 + src] == 1) << r;
    }
    cbits128[p] = cb; sbits128[p] = sb;
    __shared__ int wc[4][18];
    int w = t >> 6, lane = t & 63;
#pragma unroll
    for (int r = 0; r < 9; ++r) {
        unsigned long long b1 = __ballot((cb >> r) & 1);
        if (lane == 0) wc[w][r] = __popcll(b1);
        unsigned long long b2 = __ballot((sb >> r) & 1);
        if (lane == 0) wc[w][9 + r] = __popcll(b2);
    }
    __syncthreads();
    if (t < 18) pc[blockIdx.x * 18 + t] = wc[0][t] + wc[1][t] + wc[2][t] + wc[3][t];
}

// ---------------- ordered compaction at 128x128 (ballot scan, 2 barriers/chunk) -----
__global__ void compact_k(const int* __restrict__ sbits128, const int* __restrict__ cbits128,
                          int* __restrict__ idxlist) {
    int r = blockIdx.x, side = blockIdx.y;
    const int* bits = side ? cbits128 : sbits128;
    int* outp = idxlist + (side * 9 + r) * 16384;
    __shared__ int wcnt[4];
    __shared__ int base_s;
    int t = threadIdx.x, w = t >> 6, lane = t & 63;
    if (t == 0) base_s = 0;
    __syncthreads();
    for (int chunk = 0; chunk < 64; ++chunk) {
        int pid = chunk * 256 + t;
        int flag = (bits[pid] >> r) & 1;
        unsigned long long m = __ballot(flag);
        if (lane == 0) wcnt[w] = __popcll(m);
        __syncthreads();
        int base = base_s;
        int woff = 0;
        for (int w2 = 0; w2 < w; ++w2) woff += wcnt[w2];
        if (flag) outp[base + woff + __popcll(m & ((1ull << lane) - 1ull))] = pid;
        __syncthreads();
        if (t == 0) base_s = base + wcnt[0] + wcnt[1] + wcnt[2] + wcnt[3];
    }
}

// ---------------- weight transpose [oc][ick] -> [ick][oc] ----------------
__global__ void wtr_k(const float* __restrict__ w, float* __restrict__ wT, int OC, int ICK) {
    int i = blockIdx.x * TPB + threadIdx.x;
    int n = OC * ICK;
    if (i < n) {
        int oc = i / ICK;
        int t = i - oc * ICK;
        wT[t * OC + oc] = w[i];
    }
}

// ---------------- per-region style mean partial sums ----------------
__global__ void smean_k(const float* __restrict__ sF, const int* __restrict__ sbits,
                        float* __restrict__ ssump) {
    int c = blockIdx.x;
    int pg = blockIdx.y;
    int t = threadIdx.x;
    float acc[9];
#pragma unroll
    for (int r = 0; r < 9; ++r) acc[r] = 0.f;
    int p0 = pg * 16384;
    for (int p = p0 + t; p < p0 + 16384; p += TPB) {
        float v = sF[c * 65536 + p];
        int b = sbits[p];
#pragma unroll
        for (int r = 0; r < 9; ++r)
            if (b & (1 << r)) acc[r] += v;
    }
    __shared__ float red[9 * TPB];
#pragma unroll
    for (int r = 0; r < 9; ++r) red[r * TPB + t] = acc[r];
    __syncthreads();
    for (int off = TPB / 2; off > 0; off >>= 1) {
        if (t < off)
#pragma unroll
            for (int r = 0; r < 9; ++r) red[r * TPB + t] += red[r * TPB + t + off];
        __syncthreads();
    }
    if (t < 9) ssump[(pg * 9 + t) * 256 + c] = red[t * TPB];
}

// ---------------- sum popcount partials -> counts, active mask, style means --------
__global__ void finalize_k(const int* __restrict__ pc256, const int* __restrict__ pc128,
                           int* __restrict__ counts, int* __restrict__ activemask,
                           const float* __restrict__ ssump, float* __restrict__ sMeanArr) {
    __shared__ int cnt_s[64];
    __shared__ int am;
    int t = threadIdx.x;
    if (t < 64) cnt_s[t] = 0;
    if (t == 0) am = 0;
    __syncthreads();
    if (t < 36) {
        int grp = t / 9, r = t - grp * 9;          // grp: 0=c256 1=s256 2=c128 3=s128
        int nb = (grp < 2) ? 256 : 64;
        const int* pc = (grp < 2) ? pc256 : pc128;
        int off = (grp & 1) * 9 + r;
        int s = 0;
        for (int b = 0; b < nb; ++b) s += pc[b * 18 + off];
        int dst = grp * 16 + r;
        counts[dst] = s;
        cnt_s[dst] = s;
    }
    __syncthreads();
    if (t < 9) {
        if (cnt_s[0 + t] >= 10 && cnt_s[16 + t] >= 10 && cnt_s[32 + t] >= 10 && cnt_s[48 + t] >= 10)
            atomicOr(&am, 1 << t);
    }
    __syncthreads();
    if (t == 0) *activemask = am;
    for (int e = t; e < 2560; e += TPB) {
        int r = e >> 8, c = e & 255;
        float v = 0.f;
        if (r < 9 && ((am >> r) & 1)) {
            float s = ssump[(0 * 9 + r) * 256 + c] + ssump[(1 * 9 + r) * 256 + c]
                    + ssump[(2 * 9 + r) * 256 + c] + ssump[(3 * 9 + r) * 256 + c];
            v = s / (float)cnt_s[16 + r];
        }
        sMeanArr[e] = v;
    }
}

// ---------------- stable region ranking at 256-res: hist -> scan -> rank -------------
__global__ void hist_k(const int* __restrict__ cbits, const int* __restrict__ activemask,
                       int* __restrict__ rmap, int* __restrict__ bc) {
    int b = blockIdx.x, t = threadIdx.x;
    int p = b * 256 + t;
    int am = *activemask;
    int bits = cbits[p] & am;
    int r = bits ? (31 - __clz(bits)) : 9;
    rmap[p] = r;
    __shared__ int wc[4][10];
    int w = t >> 6, lane = t & 63;
#pragma unroll
    for (int rr = 0; rr < 10; ++rr) {
        unsigned long long m = __ballot(r == rr);
        if (lane == rr) wc[w][rr] = __popcll(m);
    }
    __syncthreads();
    if (t < 10) bc[b * 10 + t] = wc[0][t] + wc[1][t] + wc[2][t] + wc[3][t];
}

__global__ void scan_k(const int* __restrict__ bc, int* __restrict__ bbase,
                       int* __restrict__ lcnt, int* __restrict__ rbase) {
    __shared__ int tot[10], Bs[16];
    int t = threadIdx.x;
    if (t < 10) {
        int s = 0;
        for (int b = 0; b < 256; ++b) s += bc[b * 10 + t];
        tot[t] = s;
    }
    __syncthreads();
    if (t == 0) {
        int run = 0;
        for (int r = 0; r < 10; ++r) { Bs[r] = run; run += (tot[r] + 255) & ~255; }
    }
    __syncthreads();
    if (t < 10) {
        lcnt[t] = tot[t];
        rbase[t] = Bs[t];
        int run = Bs[t];
        for (int b = 0; b < 256; ++b) { bbase[b * 10 + t] = run; run += bc[b * 10 + t]; }
    }
}

__global__ void rank_k(const int* __restrict__ rmap, const int* __restrict__ bbase,
                       int* __restrict__ inv, int* __restrict__ rlist) {
    int b = blockIdx.x, t = threadIdx.x;
    int p = b * 256 + t;
    int r = rmap[p];
    __shared__ int wc[4][10];
    int w = t >> 6, lane = t & 63;
    int prefix = 0;
#pragma unroll
    for (int rr = 0; rr < 10; ++rr) {
        unsigned long long m = __ballot(r == rr);
        if (rr == r) prefix = __popcll(m & ((1ull << lane) - 1ull));
        if (lane == rr) wc[w][rr] = __popcll(m);
    }
    __syncthreads();
    int woff = 0;
    for (int w2 = 0; w2 < w; ++w2) woff += wc[w2][r];
    int g = bbase[b * 10 + r] + woff + prefix;
    inv[p] = g;
    rlist[g] = p;
}

// ---------------- helpers for 4px x 8oc conv tiling ----------------
__device__ __forceinline__ void ld8(float* d, const float* __restrict__ p) {
    float4 a = *(const float4*)p;
    float4 b = *(const float4*)(p + 4);
    d[0] = a.x; d[1] = a.y; d[2] = a.z; d[3] = a.w;
    d[4] = b.x; d[5] = b.y; d[6] = b.z; d[7] = b.w;
}

// ---------------- conv1: 1024x1024x3 -> 512x512x64, LDS ev/od, 4px x 8oc ----------
// block = half an output row (256 px); og32-split 2. Thread t: px group g=t&63
// (pixels 4g..4g+3), oc group og=t>>6 (8 ocs). Weight loads wave-uniform.
__global__ void conv1_k(const float* __restrict__ in, const float* __restrict__ wT,
                        const float* __restrict__ b, float* __restrict__ out) {
    int oy = blockIdx.x >> 1;
    int X0 = (blockIdx.x & 1) << 8;    // 0 or 256
    int og32 = blockIdx.y;
    int t = threadIdx.x;
    int g = t & 63;
    int og = __builtin_amdgcn_readfirstlane(t >> 6);   // wave-uniform 8-oc group
    __shared__ float ev[3][3][260];
    __shared__ float od[3][3][264];
    // stage interior: 3 ic x 3 rows x 128 float4 (coalesced), de-interleaved into ev/od
    for (int u = t; u < 1152; u += 256) {
        int ic = u / 384;
        int rem = u - ic * 384;
        int row = rem >> 7, q = rem & 127;
        int iy = 2 * oy - 1 + row;
        float4 v = make_float4(0.f, 0.f, 0.f, 0.f);
        if ((unsigned)iy < 1024u)
            v = *(const float4*)(in + ic * 1048576 + iy * 1024 + 2 * X0 + 4 * q);
        ev[ic][row][2 * q]     = v.x;   // x=4q
        od[ic][row][2 * q + 1] = v.y;   // x=4q+1
        ev[ic][row][2 * q + 1] = v.z;   // x=4q+2
        od[ic][row][2 * q + 2] = v.w;   // x=4q+3
    }
    // left halo (x = -1, i.e. ix = 2*X0 - 1)
    if (t < 9) {
        int ic = t / 3, row = t % 3;
        int iy = 2 * oy - 1 + row;
        int ix = 2 * X0 - 1;
        float v = 0.f;
        if ((unsigned)iy < 1024u && ix >= 0) v = in[ic * 1048576 + iy * 1024 + ix];
        od[ic][row][0] = v;
    }
    __syncthreads();
    int ocb = og32 * 32 + og * 8;
    float bias[8];
    ld8(bias, b + ocb);
    float acc[4][8];
#pragma unroll
    for (int j = 0; j < 4; ++j)
#pragma unroll
        for (int c = 0; c < 8; ++c) acc[j][c] = bias[c];
#pragma unroll
    for (int ic = 0; ic < 3; ++ic)
#pragma unroll
        for (int ky = 0; ky < 3; ++ky) {
            float4 e4 = *(const float4*)&ev[ic][ky][4 * g];
            float4 o4 = *(const float4*)&od[ic][ky][4 * g];
            float  o5 = od[ic][ky][4 * g + 4];
            float e_[4] = {e4.x, e4.y, e4.z, e4.w};
            float o_[5] = {o4.x, o4.y, o4.z, o4.w, o5};
            const float* wbase = wT + (ic * 9 + ky * 3) * 64 + ocb;
            float wA[8], wB[8], wC[8];
            ld8(wA, wbase);            // kx = 0
            ld8(wB, wbase + 64);       // kx = 1
            ld8(wC, wbase + 128);      // kx = 2
#pragma unroll
            for (int j = 0; j < 4; ++j) {
                float v0 = o_[j], v1 = e_[j], v2 = o_[j + 1];
#pragma unroll
                for (int c = 0; c < 8; ++c)
                    acc[j][c] = fmaf(wA[c], v0, fmaf(wB[c], v1, fmaf(wC[c], v2, acc[j][c])));
            }
        }
    int idx = oy * 512 + X0 + 4 * g;
#pragma unroll
    for (int c = 0; c < 8; ++c) {
        float4 o = make_float4(fmaxf(acc[0][c], 0.f), fmaxf(acc[1][c], 0.f),
                               fmaxf(acc[2][c], 0.f), fmaxf(acc[3][c], 0.f));
        *(float4*)(out + (size_t)(ocb + c) * 262144 + idx) = o;
    }
}

// ---------------- conv2: bias init, ic-split-4 atomic partials, relu ----------------
__global__ void f2init_k(const float* __restrict__ b, float* __restrict__ F2) {
    int idx = blockIdx.x * TPB + threadIdx.x;
#pragma unroll
    for (int oc = 0; oc < 32; ++oc) F2[oc * 65536 + idx] = b[oc];
}

// conv2: block = one output row (256 px), STRIDED 4px x 8oc per thread
// (thread lane g owns pixels g, g+64, g+128, g+192 -> epilogue atomics are
// lane-dense/coalesced; LDS reads are stride-1 scalar = conflict-free).
// Double-buffered ev/od LDS tile, async-STAGE split.
__device__ __forceinline__ void c2_load(const float* __restrict__ base, int oy, int t,
                                        float4& r0, float4& r1) {
    int row0 = t >> 7, q0 = t & 127;     // rows 0,1
    int iy0 = 2 * oy - 1 + row0;
    r0 = make_float4(0.f, 0.f, 0.f, 0.f);
    if ((unsigned)iy0 < 512u) r0 = *(const float4*)(base + iy0 * 512 + 4 * q0);
    r1 = make_float4(0.f, 0.f, 0.f, 0.f);
    if (t < 128) {                        // row 2: iy = 2*oy+1, always in range
        int iy1 = 2 * oy + 1;
        r1 = *(const float4*)(base + iy1 * 512 + 4 * t);
    }
}

__device__ __forceinline__ void c2_store(float (*ev)[260], float (*od)[264], int t,
                                         float4 r0, float4 r1) {
    int row0 = t >> 7, q0 = t & 127;
    ev[row0][2 * q0]     = r0.x;   // x=4q
    od[row0][2 * q0 + 1] = r0.y;   // x=4q+1
    ev[row0][2 * q0 + 1] = r0.z;   // x=4q+2
    od[row0][2 * q0 + 2] = r0.w;   // x=4q+3
    if (t < 128) {
        ev[2][2 * t]     = r1.x;
        od[2][2 * t + 1] = r1.y;
        ev[2][2 * t + 1] = r1.z;
        od[2][2 * t + 2] = r1.w;
    }
}

__device__ __forceinline__ void c2_compute(const float* __restrict__ wT, int ic,
                                           const float (*ev)[260], const float (*od)[264],
                                           int g, int og, float (*acc)[8]) {
#pragma unroll
    for (int ky = 0; ky < 3; ++ky) {
        const float* wbase = wT + (ic * 9 + ky * 3) * 32 + og * 8;
        float wA[8], wB[8], wC[8];
        ld8(wA, wbase);           // kx = 0
        ld8(wB, wbase + 32);      // kx = 1
        ld8(wC, wbase + 64);      // kx = 2
#pragma unroll
        for (int j = 0; j < 4; ++j) {
            int ox = g + 64 * j;
            float v0 = od[ky][ox];       // x = 2*ox-1  (kx=0)
            float v1 = ev[ky][ox];       // x = 2*ox    (kx=1)
            float v2 = od[ky][ox + 1];   // x = 2*ox+1  (kx=2) -> ds_read2 with v0
#pragma unroll
            for (int c = 0; c < 8; ++c)
                acc[j][c] = fmaf(wA[c], v0, fmaf(wB[c], v1, fmaf(wC[c], v2, acc[j][c])));
        }
    }
}

__global__ void conv2p_k(const float* __restrict__ in, const float* __restrict__ wT,
                         float* __restrict__ F2) {
    int oy = blockIdx.x;      // 0..255
    int icg = blockIdx.y;     // 0..3
    int t = threadIdx.x;
    int g = t & 63;
    int og = __builtin_amdgcn_readfirstlane(t >> 6);   // wave-uniform 8-oc group
    __shared__ float ev[2][3][260];
    __shared__ float od[2][3][264];
    if (t < 6) od[t / 3][t % 3][0] = 0.f;   // left halo (x = -1) stays zero, both buffers
    float acc[4][8];
#pragma unroll
    for (int j = 0; j < 4; ++j)
#pragma unroll
        for (int c = 0; c < 8; ++c) acc[j][c] = 0.f;
    int ic0 = icg * 16;
    float4 r0, r1;
    c2_load(in + ic0 * 262144, oy, t, r0, r1);
    c2_store(ev[0], od[0], t, r0, r1);
    __syncthreads();
#pragma unroll 1
    for (int i = 0; i < 16; i += 2) {
        c2_load(in + (ic0 + i + 1) * 262144, oy, t, r0, r1);   // issue loads early
        c2_compute(wT, ic0 + i, ev[0], od[0], g, og, acc);     // hide latency under FMAs
        c2_store(ev[1], od[1], t, r0, r1);                     // vmcnt drained after compute
        __syncthreads();
        if (i + 2 < 16) c2_load(in + (ic0 + i + 2) * 262144, oy, t, r0, r1);
        c2_compute(wT, ic0 + i + 1, ev[1], od[1], g, og, acc);
        if (i + 2 < 16) c2_store(ev[0], od[0], t, r0, r1);
        __syncthreads();
    }
    int rowbase = oy * 256;
#pragma unroll
    for (int c = 0; c < 8; ++c)
#pragma unroll
        for (int j = 0; j < 4; ++j)
            atomicAdd(&F2[(og * 8 + c) * 65536 + rowbase + 64 * j + g], acc[j][c]);
}

__global__ void relu2_k(float* __restrict__ F2) {
    int i = blockIdx.x * TPB + threadIdx.x;
    float4* p = (float4*)F2;
    float4 v = p[i];
    v.x = fmaxf(v.x, 0.f); v.y = fmaxf(v.y, 0.f);
    v.z = fmaxf(v.z, 0.f); v.w = fmaxf(v.w, 0.f);
    p[i] = v;
}

// ---------------- conv3: bias init + ic-split-4 atomic partials (no relu) ------------
__global__ void f3init_k(const float* __restrict__ b, float* __restrict__ F3) {
    int idx = blockIdx.x * TPB + threadIdx.x;
#pragma unroll
    for (int oc = 0; oc < 16; ++oc) F3[oc * 16384 + idx] = b[oc];
}

__global__ void conv3p_k(const float* __restrict__ in, const float* __restrict__ wT,
                         float* __restrict__ F3) {
    int idx = blockIdx.x * TPB + threadIdx.x;
    int icg = blockIdx.y;
    int ox = idx & 127, oy = idx >> 7;
    float acc[16];
#pragma unroll
    for (int oc = 0; oc < 16; ++oc) acc[oc] = 0.f;
    for (int ic = icg * 8; ic < icg * 8 + 8; ++ic) {
        const float* base = in + ic * 65536;
#pragma unroll
        for (int ky = 0; ky < 3; ++ky) {
            int iy = 2 * oy - 1 + ky;
            if ((unsigned)iy < 256u)
#pragma unroll
                for (int kx = 0; kx < 3; ++kx) {
                    int ix = 2 * ox - 1 + kx;
                    if ((unsigned)ix < 256u) {
                        float v = base[iy * 256 + ix];
                        const float4* wp = (const float4*)(wT + (ic * 9 + ky * 3 + kx) * 16);
#pragma unroll
                        for (int q = 0; q < 4; ++q) {
                            float4 w4 = wp[q];
                            acc[q * 4 + 0] = fmaf(w4.x, v, acc[q * 4 + 0]);
                            acc[q * 4 + 1] = fmaf(w4.y, v, acc[q * 4 + 1]);
                            acc[q * 4 + 2] = fmaf(w4.z, v, acc[q * 4 + 2]);
                            acc[q * 4 + 3] = fmaf(w4.w, v, acc[q * 4 + 3]);
                        }
                    }
                }
        }
    }
#pragma unroll
    for (int oc = 0; oc < 16; ++oc) atomicAdd(&F3[oc * 16384 + idx], acc[oc]);
}

// ---------------- adaptive max pool over ordered compacted indices ----------------
__global__ void pool_k(const float* __restrict__ f3, const int* __restrict__ idxbase,
                       const int* __restrict__ cnt, float* __restrict__ pooled) {
    int r = blockIdx.x >> 4;
    int c = blockIdx.x & 15;
    int j = threadIdx.x;
    int n = cnt[r];
    float m = 0.f;
    if (n >= 1) {
        int start = (j * n) >> 8;
        int end = ((j + 1) * n + 255) >> 8;
        const int* il = idxbase + r * 16384;
        m = -__builtin_inff();
        for (int t = start; t < end; ++t) m = fmaxf(m, f3[c * 16384 + il[t]]);
    }
    pooled[(r * 16 + c) * 256 + j] = m;
}

// ---------------- FC: M[side][r][row] (9 cols batched per row-block) ----------------
__global__ void fc_k(const float* __restrict__ fcw_s, const float* __restrict__ fcb_s,
                     const float* __restrict__ fcw_c, const float* __restrict__ fcb_c,
                     const float* __restrict__ pooled, float* __restrict__ Mout) {
    int row = blockIdx.x;
    int side = blockIdx.y;
    const float* fcw = side ? fcw_c : fcw_s;
    const float* fcb = side ? fcb_c : fcb_s;
    const float* P = pooled + side * 9 * 4096;
    int t = threadIdx.x;
    float acc[9];
#pragma unroll
    for (int r = 0; r < 9; ++r) acc[r] = 0.f;
    for (int k = t; k < 4096; k += TPB) {
        float w = fcw[row * 4096 + k];
#pragma unroll
        for (int r = 0; r < 9; ++r) acc[r] = fmaf(w, P[r * 4096 + k], acc[r]);
    }
    __shared__ float red[9 * TPB];
#pragma unroll
    for (int r = 0; r < 9; ++r) red[r * TPB + t] = acc[r];
    __syncthreads();
    for (int off = TPB / 2; off > 0; off >>= 1) {
        if (t < off)
#pragma unroll
            for (int r = 0; r < 9; ++r) red[r * TPB + t] += red[r * TPB + t + off];
        __syncthreads();
    }
    if (t < 9) Mout[(side * 9 + t) * 4096 + row] = red[t * TPB] + fcb[row];
}

// ---------------- Xc^T = (compress_w @ cF)^T, m-split 4 ----------------
__global__ void xgemm_k(const float* __restrict__ cF, const float* __restrict__ cwT,
                        float* __restrict__ XcT) {
    int p = blockIdx.x * TPB + threadIdx.x;
    int m0 = blockIdx.y * 16;
    float acc[16];
#pragma unroll
    for (int m = 0; m < 16; ++m) acc[m] = 0.f;
    for (int k0 = 0; k0 < 256; k0 += 4) {
        float xv[4];
#pragma unroll
        for (int i = 0; i < 4; ++i) xv[i] = cF[(k0 + i) * 65536 + p];
#pragma unroll
        for (int i = 0; i < 4; ++i) {
            const float4* wp = (const float4*)(cwT + (k0 + i) * 64 + m0);
#pragma unroll
            for (int q = 0; q < 4; ++q) {
                float4 w4 = wp[q];
                acc[q * 4 + 0] = fmaf(w4.x, xv[i], acc[q * 4 + 0]);
                acc[q * 4 + 1] = fmaf(w4.y, xv[i], acc[q * 4 + 1]);
                acc[q * 4 + 2] = fmaf(w4.z, xv[i], acc[q * 4 + 2]);
                acc[q * 4 + 3] = fmaf(w4.w, xv[i], acc[q * 4 + 3]);
            }
        }
    }
    float4* op = (float4*)(XcT + p * 64 + m0);
#pragma unroll
    for (int q = 0; q < 4; ++q)
        op[q] = make_float4(acc[q * 4 + 0], acc[q * 4 + 1], acc[q * 4 + 2], acc[q * 4 + 3]);
}

// ---------------- mu from Xc^T ----------------
__global__ void muacc_k(const float* __restrict__ XcT, float* __restrict__ musum) {
    int t = threadIdx.x;
    int m = t & 63, sub = t >> 6;
    int p0 = blockIdx.x * 256;
    float a = 0.f;
    for (int i = 0; i < 64; ++i) a += XcT[(p0 + sub + i * 4) * 64 + m];
    __shared__ float red[TPB];
    red[t] = a;
    __syncthreads();
    if (t < 64) atomicAdd(&musum[t], red[t] + red[t + 64] + red[t + 128] + red[t + 192]);
}

__global__ void mufin_k(const float* __restrict__ musum, float* __restrict__ mu) {
    int t = threadIdx.x;
    if (t < 64) mu[t] = musum[t] * (1.f / 65536.f);
}

// ---------------- U/V precompute ----------------
__global__ void uprep1_k(const float* __restrict__ uw, const float* __restrict__ M,
                         float* __restrict__ P) {
    int idx = blockIdx.x * TPB + threadIdx.x;
    int r = idx / 16384;
    int rem = idx & 16383;
    int c = rem >> 6, k = rem & 63;
    float a = 0.f;
#pragma unroll 8
    for (int i = 0; i < 64; ++i) a = fmaf(uw[c * 64 + i], M[r * 4096 + i * 64 + k], a);
    P[idx] = a;
}

__global__ void uprep2_k(const float* __restrict__ uw, const float* __restrict__ M,
                         const float* __restrict__ P, float* __restrict__ U) {
    int idx = blockIdx.x * TPB + threadIdx.x;
    int r = idx / 16384;
    int rem = idx & 16383;
    int c = rem >> 6, j = rem & 63;
    if (r == 9) { U[idx] = uw[c * 64 + j]; return; }
    float a = 0.f;
#pragma unroll 8
    for (int k = 0; k < 64; ++k) a = fmaf(P[r * 16384 + c * 64 + k], M[(9 + r) * 4096 + k * 64 + j], a);
    U[idx] = a;
}

__global__ void uprep3_k(const float* __restrict__ U, const float* __restrict__ mu,
                         const float* __restrict__ uzb, const float* __restrict__ sMeanArr,
                         float* __restrict__ V) {
    int r = blockIdx.x;
    int c = threadIdx.x;
    float a = uzb[c] + sMeanArr[r * 256 + c];
#pragma unroll 8
    for (int j = 0; j < 64; ++j) a -= U[r * 16384 + c * 64 + j] * mu[j];
    V[r * 256 + c] = a;
}

// ---------------- Yc[oc][rank] = U_r @ Xc + V_r  (coalesced full-line writes) --------
__global__ void ygemm_k(const float* __restrict__ XcT, const float* __restrict__ U,
                        const float* __restrict__ V, const int* __restrict__ lcnt,
                        const int* __restrict__ rbase, const int* __restrict__ rlist,
                        float* __restrict__ Yc) {
    int r = blockIdx.x >> 8;
    int c = blockIdx.x & 255;
    int ocg = blockIdx.y;
    int n = lcnt[r];
    int start = c * 256;
    if (start >= n) return;
    int i = start + threadIdx.x;
    bool valid = i < n;
    int gi = rbase[r] + (valid ? i : n - 1);
    int pix = rlist[gi];
    float4 xv[16];
    const float4* xp = (const float4*)(XcT + (size_t)pix * 64);
#pragma unroll
    for (int q = 0; q < 16; ++q) xv[q] = xp[q];
    const float* Ur = U + r * 16384 + ocg * 4096;
    const float* Vr = V + r * 256 + ocg * 64;
#pragma unroll 4
    for (int oc = 0; oc < 64; ++oc) {
        float a = Vr[oc];
        const float4* up = (const float4*)(Ur + oc * 64);
#pragma unroll
        for (int q = 0; q < 16; ++q) {
            float4 u4 = up[q];
            a = fmaf(u4.x, xv[q].x, a);
            a = fmaf(u4.y, xv[q].y, a);
            a = fmaf(u4.z, xv[q].z, a);
            a = fmaf(u4.w, xv[q].w, a);
        }
        if (valid) Yc[(size_t)(ocg * 64 + oc) * YC_STRIDE + gi] = a;   // store now: no acc[], no spill
    }
}

// ---------------- merge: out[oc][p] = Yc[oc][inv[p]]  (coalesced output writes) ------
__global__ void merge_k(const float* __restrict__ Yc, const int* __restrict__ inv,
                        float* __restrict__ out) {
    int p = blockIdx.x * TPB + threadIdx.x;
    int oc0 = blockIdx.y * 4;
    int gi = inv[p];
#pragma unroll
    for (int j = 0; j < 4; ++j)
        out[(size_t)(oc0 + j) * 65536 + p] = Yc[(size_t)(oc0 + j) * YC_STRIDE + gi];
}

// ---------------- launch ----------------
extern "C" void kernel_launch(void* const* d_in, const int* in_sizes, int n_in,
                              void* d_out, int out_size, void* d_ws, size_t ws_size,
                              hipStream_t stream) {
    const float* cF         = (const float*)d_in[0];
    const float* sF         = (const float*)d_in[1];
    const float* content    = (const float*)d_in[2];
    const float* style      = (const float*)d_in[3];
    const int*   cmasks     = (const int*)d_in[4];
    const int*   smasks     = (const int*)d_in[5];
    const float* compress_w = (const float*)d_in[6];
    const float* unzip_w    = (const float*)d_in[8];
    const float* unzip_b    = (const float*)d_in[9];
    const float* s_w1 = (const float*)d_in[10]; const float* s_b1 = (const float*)d_in[11];
    const float* s_w2 = (const float*)d_in[12]; const float* s_b2 = (const float*)d_in[13];
    const float* s_w3 = (const float*)d_in[14]; const float* s_b3 = (const float*)d_in[15];
    const float* s_fcw = (const float*)d_in[16]; const float* s_fcb = (const float*)d_in[17];
    const float* c_w1 = (const float*)d_in[18]; const float* c_b1 = (const float*)d_in[19];
    const float* c_w2 = (const float*)d_in[20]; const float* c_b2 = (const float*)d_in[21];
    const float* c_w3 = (const float*)d_in[22]; const float* c_b3 = (const float*)d_in[23];
    const float* c_fcw = (const float*)d_in[24]; const float* c_fcb = (const float*)d_in[25];
    float* out = (float*)d_out;
    char* ws = (char*)d_ws;
#define WF(o) ((float*)(ws + (o)))
#define WI(o) ((int*)(ws + (o)))

    init_k<<<1, TPB, 0, stream>>>(WI(0), 256);   // counts, active, musum
    bits_k<<<256, TPB, 0, stream>>>(cmasks, smasks, WI(OFF_CBITS), WI(OFF_SBITS), WI(OFF_PC256));
    bits128_k<<<64, TPB, 0, stream>>>(cmasks, smasks, WI(OFF_CBITS128), WI(OFF_SBITS128), WI(OFF_PC128));
    compact_k<<<dim3(9, 2), TPB, 0, stream>>>(WI(OFF_SBITS128), WI(OFF_CBITS128), WI(OFF_IDX));
    smean_k<<<dim3(256, 4), TPB, 0, stream>>>(sF, WI(OFF_SBITS), WF(OFF_SSUM));
    finalize_k<<<1, TPB, 0, stream>>>(WI(OFF_PC256), WI(OFF_PC128), WI(OFF_COUNTS),
                                      WI(OFF_ACTIVE), WF(OFF_SSUM), WF(OFF_SMEAN));

    // stable region ranking
    hist_k<<<256, TPB, 0, stream>>>(WI(OFF_CBITS), WI(OFF_ACTIVE), WI(OFF_INV) /*tmp rmap*/, WI(OFF_BC));
    scan_k<<<1, TPB, 0, stream>>>(WI(OFF_BC), WI(OFF_BBASE), WI(OFF_LCNT), WI(OFF_RBASE));
    rank_k<<<256, TPB, 0, stream>>>(WI(OFF_INV) /*rmap in*/, WI(OFF_BBASE), WI(OFF_INV), WI(OFF_RLIST));

    // Xc^T (compress)
    wtr_k<<<64, TPB, 0, stream>>>(compress_w, WF(OFF_CWT), 64, 256);
    xgemm_k<<<dim3(256, 4), TPB, 0, stream>>>(cF, WF(OFF_CWT), WF(OFF_XCT));
    muacc_k<<<256, TPB, 0, stream>>>(WF(OFF_XCT), WF(OFF_MUSUM));
    mufin_k<<<1, 64, 0, stream>>>(WF(OFF_MUSUM), WF(OFF_MU));

    // style CNN
    wtr_k<<<7, TPB, 0, stream>>>(s_w1, WF(OFF_W1T), 64, 27);
    wtr_k<<<72, TPB, 0, stream>>>(s_w2, WF(OFF_W2T), 32, 576);
    wtr_k<<<18, TPB, 0, stream>>>(s_w3, WF(OFF_W3T), 16, 288);
    conv1_k<<<dim3(1024, 2), TPB, 0, stream>>>(style, WF(OFF_W1T), s_b1, WF(OFF_F1));
    f2init_k<<<256, TPB, 0, stream>>>(s_b2, WF(OFF_F2));
    conv2p_k<<<dim3(256, 4), TPB, 0, stream>>>(WF(OFF_F1), WF(OFF_W2T), WF(OFF_F2));
    relu2_k<<<2048, TPB, 0, stream>>>(WF(OFF_F2));
    f3init_k<<<64, TPB, 0, stream>>>(s_b3, WF(OFF_F3));
    conv3p_k<<<dim3(64, 4), TPB, 0, stream>>>(WF(OFF_F2), WF(OFF_W3T), WF(OFF_F3));
    pool_k<<<144, TPB, 0, stream>>>(WF(OFF_F3), WI(OFF_IDX), WI(OFF_COUNTS) + 48, WF(OFF_POOLED));

    // content CNN
    wtr_k<<<7, TPB, 0, stream>>>(c_w1, WF(OFF_W1T), 64, 27);
    wtr_k<<<72, TPB, 0, stream>>>(c_w2, WF(OFF_W2T), 32, 576);
    wtr_k<<<18, TPB, 0, stream>>>(c_w3, WF(OFF_W3T), 16, 288);
    conv1_k<<<dim3(1024, 2), TPB, 0, stream>>>(content, WF(OFF_W1T), c_b1, WF(OFF_F1));
    f2init_k<<<256, TPB, 0, stream>>>(c_b2, WF(OFF_F2));
    conv2p_k<<<dim3(256, 4), TPB, 0, stream>>>(WF(OFF_F1), WF(OFF_W2T), WF(OFF_F2));
    relu2_k<<<2048, TPB, 0, stream>>>(WF(OFF_F2));
    f3init_k<<<64, TPB, 0, stream>>>(c_b3, WF(OFF_F3));
    conv3p_k<<<dim3(64, 4), TPB, 0, stream>>>(WF(OFF_F2), WF(OFF_W3T), WF(OFF_F3));
    pool_k<<<144, TPB, 0, stream>>>(WF(OFF_F3), WI(OFF_IDX) + 9 * 16384, WI(OFF_COUNTS) + 32,
                                    WF(OFF_POOLED) + 9 * 4096);

    fc_k<<<dim3(4096, 2), TPB, 0, stream>>>(s_fcw, s_fcb, c_fcw, c_fcb, WF(OFF_POOLED), WF(OFF_M));

    uprep1_k<<<576, TPB, 0, stream>>>(unzip_w, WF(OFF_M), WF(OFF_P));
    uprep2_k<<<640, TPB, 0, stream>>>(unzip_w, WF(OFF_M), WF(OFF_P), WF(OFF_U));
    uprep3_k<<<10, TPB, 0, stream>>>(WF(OFF_U), WF(OFF_MU), unzip_b, WF(OFF_SMEAN), WF(OFF_V));

    // final GEMM into rank-compacted Yc (reuses F1/F2 space), then dense merge
    ygemm_k<<<dim3(2560, 4), TPB, 0, stream>>>(WF(OFF_XCT), WF(OFF_U), WF(OFF_V),
                                               WI(OFF_LCNT), WI(OFF_RBASE), WI(OFF_RLIST), WF(OFF_YC));
    merge_k<<<dim3(256, 64), TPB, 0, stream>>>(WF(OFF_YC), WI(OFF_INV), out);
}